// Round 6
// baseline (228.742 us; speedup 1.0000x reference)
//
#include <hip/hip_runtime.h>
#include <cstdint>
#include <cstddef>

#define NND 100000
#define NED 640000
#define NSCAN_B 98          // ceil(NND/1024)

typedef unsigned int u32;
typedef unsigned short u16;
typedef __attribute__((ext_vector_type(8))) short bf16x8;
typedef __attribute__((ext_vector_type(4))) float f32x4;

// ---------------------------------------------------------------------------
// helpers: fp32 <-> bf16 (RNE), async global->LDS 16B
// ---------------------------------------------------------------------------
__device__ __forceinline__ u16 f2b(float f) {
    u32 u = __float_as_uint(f);
    return (u16)((u + 0x7fffu + ((u >> 16) & 1u)) >> 16);
}
__device__ __forceinline__ float b2f(u16 b) {
    return __uint_as_float(((u32)b) << 16);
}
__device__ __forceinline__ u32 pack2(float a, float b) {
    return (u32)f2b(a) | ((u32)f2b(b) << 16);
}
__device__ __forceinline__ void gload16(u16* lds, const u16* g) {
    __builtin_amdgcn_global_load_lds(
        (const __attribute__((address_space(1))) u32*)g,
        (__attribute__((address_space(3))) u32*)lds,
        16, 0, 0);
}

// ---------------------------------------------------------------------------
// degree count (int) and dinv
// ---------------------------------------------------------------------------
__global__ __launch_bounds__(256)
void deg_kernel(const int* __restrict__ ei, int* __restrict__ cnt) {
    const int e = blockIdx.x * 256 + threadIdx.x;
    if (e < NED) atomicAdd(&cnt[ei[NED + e]], 1);
}

__global__ __launch_bounds__(256)
void dinv_kernel(const int* __restrict__ cnt, float* __restrict__ dinv) {
    const int i = blockIdx.x * 256 + threadIdx.x;
    if (i < NND) dinv[i] = rsqrtf(1.0f + (float)cnt[i]);
}

// ---------------------------------------------------------------------------
// exclusive scan of cnt[NND] -> offs[NND+1]
// ---------------------------------------------------------------------------
__global__ __launch_bounds__(256)
void scanA(const int* __restrict__ cnt, int* __restrict__ offs, int* __restrict__ bsum) {
    __shared__ int s[256];
    const int t = threadIdx.x;
    const int base = blockIdx.x * 1024 + t * 4;
    int c0 = (base + 0 < NND) ? cnt[base + 0] : 0;
    int c1 = (base + 1 < NND) ? cnt[base + 1] : 0;
    int c2 = (base + 2 < NND) ? cnt[base + 2] : 0;
    int c3 = (base + 3 < NND) ? cnt[base + 3] : 0;
    const int local = c0 + c1 + c2 + c3;
    s[t] = local;
    __syncthreads();
    for (int off = 1; off < 256; off <<= 1) {
        int v = (t >= off) ? s[t - off] : 0;
        __syncthreads();
        s[t] += v;
        __syncthreads();
    }
    const int excl = s[t] - local;
    if (t == 255) bsum[blockIdx.x] = s[255];
    if (base + 0 < NND) offs[base + 0] = excl;
    if (base + 1 < NND) offs[base + 1] = excl + c0;
    if (base + 2 < NND) offs[base + 2] = excl + c0 + c1;
    if (base + 3 < NND) offs[base + 3] = excl + c0 + c1 + c2;
}

__global__ __launch_bounds__(64)
void scanB(int* __restrict__ bsum, int* __restrict__ offs) {
    if (threadIdx.x == 0) {
        int run = 0;
        for (int b = 0; b < NSCAN_B; ++b) { int v = bsum[b]; bsum[b] = run; run += v; }
        offs[NND] = NED;
    }
}

__global__ __launch_bounds__(256)
void scanC(int* __restrict__ offs, const int* __restrict__ bsum, int* __restrict__ cursor) {
    const int i = blockIdx.x * 256 + threadIdx.x;
    if (i < NND) {
        const int v = offs[i] + bsum[i >> 10];
        offs[i] = v;
        cursor[i] = v;
    }
}

// fill CSR sorted by dst; packed 8B record {src, bits(dinv[src]*dinv[dst])}
// -> ONE random cache line touched per edge instead of two.
__global__ __launch_bounds__(256)
void fill_kernel(const int* __restrict__ ei, const float* __restrict__ dinv,
                 int* __restrict__ cursor, uint2* __restrict__ recS) {
    const int e = blockIdx.x * 256 + threadIdx.x;
    if (e < NED) {
        const int src = ei[e], dst = ei[NED + e];
        const int p = atomicAdd(&cursor[dst], 1);
        recS[p] = make_uint2((u32)src, __float_as_uint(dinv[src] * dinv[dst]));
    }
}

// ---------------------------------------------------------------------------
// conversions: x -> bf16 ; W1,W2 -> transposed bf16 (Wt[n][k])
// ---------------------------------------------------------------------------
__global__ __launch_bounds__(256)
void cvt_x_kernel(const float* __restrict__ x, u32* __restrict__ xb) {
    const int i = blockIdx.x * 256 + threadIdx.x;      // exactly 3,200,000 threads
    const float4 v = *(const float4*)&x[(size_t)i * 4];
    xb[(size_t)i * 2 + 0] = pack2(v.x, v.y);
    xb[(size_t)i * 2 + 1] = pack2(v.z, v.w);
}

__global__ __launch_bounds__(256)
void cvt_w_kernel(const float* __restrict__ W1, const float* __restrict__ W2,
                  u16* __restrict__ W1t, u16* __restrict__ W2t) {
    const int i = blockIdx.x * 256 + threadIdx.x;      // 49152 threads
    if (i < 128 * 256) {
        const int k = i >> 8, n = i & 255;
        W1t[n * 128 + k] = f2b(W1[i]);
    } else {
        const int j = i - 128 * 256;                   // j < 256*64
        const int k = j >> 6, n = j & 63;
        W2t[n * 256 + k] = f2b(W2[j]);
    }
}

// ---------------------------------------------------------------------------
// CSR gather (bf16), 8-wide predicated edge groups, packed edge records.
// z[d] = dinv[d]^2*x[d] + sum_e wt[e]*x[src[e]]
// ---------------------------------------------------------------------------
__global__ __launch_bounds__(256)
void gather128b(const int* __restrict__ offs, const uint2* __restrict__ recS,
                const float* __restrict__ dinv,
                const u32* __restrict__ xb, u32* __restrict__ zb) {
    const int d    = (blockIdx.x * 256 + threadIdx.x) >> 6;
    const int lane = threadIdx.x & 63;
    if (d >= NND) return;
    const int beg = offs[d], end = offs[d + 1];
    const float dd = dinv[d];
    const u32 s = xb[(size_t)d * 64 + lane];
    float ax = b2f((u16)s) * dd * dd;
    float ay = b2f((u16)(s >> 16)) * dd * dd;
    for (int e = beg; e < end; e += 8) {
        uint2 r[8]; float wi[8]; u32 vi[8];
        #pragma unroll
        for (int j = 0; j < 8; ++j) {
            const int ee = e + j;
            r[j] = recS[(ee < end) ? ee : (end - 1)];
        }
        #pragma unroll
        for (int j = 0; j < 8; ++j) {
            wi[j] = (e + j < end) ? __uint_as_float(r[j].y) : 0.0f;
            vi[j] = xb[(size_t)r[j].x * 64 + lane];
        }
        #pragma unroll
        for (int j = 0; j < 8; ++j) {
            ax = fmaf(wi[j], b2f((u16)vi[j]), ax);
            ay = fmaf(wi[j], b2f((u16)(vi[j] >> 16)), ay);
        }
    }
    zb[(size_t)d * 64 + lane] = pack2(ax, ay);
}

// out[d] += sum_e wt[e]*xw2[src[e]]   (out pre-init by gemm2 epilogue; xw2 bf16)
__global__ __launch_bounds__(256)
void gather64b(const int* __restrict__ offs, const uint2* __restrict__ recS,
               const u16* __restrict__ xwb, float* __restrict__ out) {
    const int d    = (blockIdx.x * 256 + threadIdx.x) >> 6;
    const int lane = threadIdx.x & 63;
    if (d >= NND) return;
    const int beg = offs[d], end = offs[d + 1];
    float* p = &out[(size_t)d * 64 + lane];
    float acc = *p;
    for (int e = beg; e < end; e += 8) {
        uint2 r[8]; float wi[8]; u16 vi[8];
        #pragma unroll
        for (int j = 0; j < 8; ++j) {
            const int ee = e + j;
            r[j] = recS[(ee < end) ? ee : (end - 1)];
        }
        #pragma unroll
        for (int j = 0; j < 8; ++j) {
            wi[j] = (e + j < end) ? __uint_as_float(r[j].y) : 0.0f;
            vi[j] = xwb[(size_t)r[j].x * 64 + lane];
        }
        #pragma unroll
        for (int j = 0; j < 8; ++j)
            acc = fmaf(wi[j], b2f(vi[j]), acc);
    }
    *p = acc;
}

// ---------------------------------------------------------------------------
// bf16 MFMA GEMM: C = A[M][K] @ Bt[N][K]^T, 4 waves, 64x64 per wave, BK=32.
// EPI 0: O1(bf16) = relu(acc + bias[col])                        (layer-1 h)
// EPI 1: O1(bf16) = acc ; O2(fp32) = dinv[row]^2*acc + bias[col] (xw2 + out-init)
// ---------------------------------------------------------------------------
template<int BM, int BN, int WM, int WN, int EPI>
__global__ __launch_bounds__(256)
void gemm_mfma(const u16* __restrict__ A, const u16* __restrict__ Bt,
               const float* __restrict__ bias, const float* __restrict__ dinv,
               void* __restrict__ O1, float* __restrict__ O2,
               int M, int N, int K)
{
    __shared__ __align__(16) u16 As[BM * 32];
    __shared__ __align__(16) u16 Bs[BN * 32];
    const int tid  = threadIdx.x;
    const int lane = tid & 63;
    const int wid  = tid >> 6;
    const int wm   = wid % WM;
    const int wn   = wid / WM;
    const int row0 = blockIdx.x * BM;
    const int col0 = blockIdx.y * BN;
    const int wrow0 = wm * 64, wcol0 = wn * 64;

    f32x4 acc[4][4];
    #pragma unroll
    for (int i = 0; i < 4; ++i)
        #pragma unroll
        for (int j = 0; j < 4; ++j) acc[i][j] = (f32x4){0.f, 0.f, 0.f, 0.f};

    const int lr = lane >> 2;          // 0..15: row within 16-row load chunk
    const int lk = (lane & 3) * 8;     // k-element offset (16B granule)

    for (int kt = 0; kt < K; kt += 32) {
        #pragma unroll
        for (int j = 0; j < BM / 64; ++j) {
            const int li = wid * (BM / 64) + j;            // 16 rows per load
            const int r  = li * 16 + lr;
            const int rg = (row0 + r < M) ? (row0 + r) : (M - 1);
            gload16(&As[li * 512], &A[(size_t)rg * K + kt + lk]);
        }
        #pragma unroll
        for (int j = 0; j < BN / 64; ++j) {
            const int li = wid * (BN / 64) + j;
            const int n  = li * 16 + lr;
            gload16(&Bs[li * 512], &Bt[(size_t)(col0 + n) * K + kt + lk]);
        }
        __syncthreads();

        bf16x8 af[4], bfr[4];
        #pragma unroll
        for (int mi = 0; mi < 4; ++mi)
            af[mi] = *(const bf16x8*)&As[(wrow0 + mi * 16 + (lane & 15)) * 32 + (lane >> 4) * 8];
        #pragma unroll
        for (int ni = 0; ni < 4; ++ni)
            bfr[ni] = *(const bf16x8*)&Bs[(wcol0 + ni * 16 + (lane & 15)) * 32 + (lane >> 4) * 8];
        #pragma unroll
        for (int mi = 0; mi < 4; ++mi)
            #pragma unroll
            for (int ni = 0; ni < 4; ++ni)
                acc[mi][ni] = __builtin_amdgcn_mfma_f32_16x16x32_bf16(
                    af[mi], bfr[ni], acc[mi][ni], 0, 0, 0);
        __syncthreads();
    }

    const int rb = (lane >> 4) * 4;
    const int cl = lane & 15;
    #pragma unroll
    for (int mi = 0; mi < 4; ++mi) {
        #pragma unroll
        for (int r = 0; r < 4; ++r) {
            const int row = row0 + wrow0 + mi * 16 + rb + r;
            if (row >= M) continue;
            #pragma unroll
            for (int ni = 0; ni < 4; ++ni) {
                const int col = col0 + wcol0 + ni * 16 + cl;
                const float v = acc[mi][ni][r];
                if constexpr (EPI == 0) {
                    ((u16*)O1)[(size_t)row * N + col] = f2b(fmaxf(v + bias[col], 0.f));
                } else {
                    ((u16*)O1)[(size_t)row * N + col] = f2b(v);
                    const float dd = dinv[row];
                    O2[(size_t)row * N + col] = fmaf(dd * dd, v, bias[col]);
                }
            }
        }
    }
}

// ---------------------------------------------------------------------------
extern "C" void kernel_launch(void* const* d_in, const int* in_sizes, int n_in,
                              void* d_out, int out_size, void* d_ws, size_t ws_size,
                              hipStream_t stream)
{
    const float* x  = (const float*)d_in[0];
    const int*   ei = (const int*)d_in[1];   // [2, E]: src row then dst row
    const float* W1 = (const float*)d_in[2];
    const float* b1 = (const float*)d_in[3];
    const float* W2 = (const float*)d_in[4];
    const float* b2 = (const float*)d_in[5];
    float* out = (float*)d_out;

    // workspace layout (bytes, all 128-aligned):
    char* ws = (char*)d_ws;
    float* dinv = (float*)(ws + 0);            //    400,000 -> 400,128
    int*   cnt  = (int*)  (ws + 400128);       //    400,000 -> 800,128 (reused as cursor)
    int*   offs = (int*)  (ws + 800128);       //    400,004 -> 1,200,256
    int*   bsum = (int*)  (ws + 1200256);      //        512 -> 1,200,768
    uint2* recS = (uint2*)(ws + 1200768);      //  5,120,000 -> 6,320,768  (packed src+wt)
    u32*   xb   = (u32*)  (ws + 6320768);      // 25,600,000 -> 31,920,768  (x bf16)
    u32*   zb   = (u32*)  (ws + 31920768);     // 25,600,000 -> 57,520,768  (Ax bf16)
    u16*   hb   = (u16*)  (ws + 57520768);     // 51,200,000 -> 108,720,768 (h bf16)
    u16*   W1t  = (u16*)  (ws + 108720768);    //     65,536 -> 108,786,304
    u16*   W2t  = (u16*)  (ws + 108786304);    //     32,768 -> 108,819,072
    u16*   xwb  = (u16*)  (ws + 108819072);    // 12,800,000 -> 121,619,072 (xw2 bf16)

    // ---- CSR build + dinv + packed edge records ----
    hipMemsetAsync(cnt, 0, NND * sizeof(int), stream);
    deg_kernel<<<(NED + 255) / 256, 256, 0, stream>>>(ei, cnt);
    dinv_kernel<<<(NND + 255) / 256, 256, 0, stream>>>(cnt, dinv);
    scanA<<<NSCAN_B, 256, 0, stream>>>(cnt, offs, bsum);
    scanB<<<1, 64, 0, stream>>>(bsum, offs);
    scanC<<<(NND + 255) / 256, 256, 0, stream>>>(offs, bsum, cnt);
    fill_kernel<<<(NED + 255) / 256, 256, 0, stream>>>(ei, dinv, cnt, recS);

    // ---- precision conversions ----
    cvt_x_kernel<<<12500, 256, 0, stream>>>(x, xb);          // 12.8M floats
    cvt_w_kernel<<<192, 256, 0, stream>>>(W1, W2, W1t, W2t);

    // ---- layer 1: z = A~ x  (bf16 gather), h = relu(z@W1 + b1) ----
    gather128b<<<(NND * 64) / 256 + 1, 256, 0, stream>>>(offs, recS, dinv, xb, zb);
    gemm_mfma<128, 128, 2, 2, 0><<<dim3(782, 2), 256, 0, stream>>>(
        (const u16*)zb, W1t, b1, nullptr, hb, nullptr, NND, 256, 128);

    // ---- layer 2: xw2 = h@W2 (bf16), out = dinv^2*xw2 + b2, then gather ----
    gemm_mfma<256, 64, 4, 1, 1><<<dim3(391, 1), 256, 0, stream>>>(
        hb, W2t, b2, dinv, xwb, out, NND, 64, 256);
    gather64b<<<(NND * 64) / 256 + 1, 256, 0, stream>>>(offs, recS, xwb, out);
}

// Round 7
// 209.227 us; speedup vs baseline: 1.0933x; 1.0933x over previous
//
#include <hip/hip_runtime.h>
#include <cstdint>
#include <cstddef>

#define NND 100000
#define NED 640000
#define NSCAN_B 98          // ceil(NND/1024)

typedef unsigned int u32;
typedef unsigned short u16;
typedef __attribute__((ext_vector_type(8))) short bf16x8;
typedef __attribute__((ext_vector_type(4))) float f32x4;

// ---------------------------------------------------------------------------
// helpers: fp32 <-> bf16 (RNE), async global->LDS 16B
// ---------------------------------------------------------------------------
__device__ __forceinline__ u16 f2b(float f) {
    u32 u = __float_as_uint(f);
    return (u16)((u + 0x7fffu + ((u >> 16) & 1u)) >> 16);
}
__device__ __forceinline__ float b2f(u16 b) {
    return __uint_as_float(((u32)b) << 16);
}
__device__ __forceinline__ u32 pack2(float a, float b) {
    return (u32)f2b(a) | ((u32)f2b(b) << 16);
}
__device__ __forceinline__ void gload16(u16* lds, const u16* g) {
    __builtin_amdgcn_global_load_lds(
        (const __attribute__((address_space(1))) u32*)g,
        (__attribute__((address_space(3))) u32*)lds,
        16, 0, 0);
}

// ---------------------------------------------------------------------------
// fused pre-pass: blocks [0,2500) deg atomics ; [2500,15000) cvt x->bf16 ;
// [15000,15192) cvt W1,W2 -> transposed bf16. All independent.
// ---------------------------------------------------------------------------
__global__ __launch_bounds__(256)
void fused_pre(const int* __restrict__ ei, int* __restrict__ cnt,
               const float* __restrict__ x, u32* __restrict__ xb,
               const float* __restrict__ W1, const float* __restrict__ W2,
               u16* __restrict__ W1t, u16* __restrict__ W2t) {
    const int b = blockIdx.x;
    if (b < 2500) {
        const int e = b * 256 + threadIdx.x;              // 2500*256 == NED exact
        atomicAdd(&cnt[ei[NED + e]], 1);
    } else if (b < 15000) {
        const int i = (b - 2500) * 256 + threadIdx.x;     // < 3,200,000 exact
        const float4 v = *(const float4*)&x[(size_t)i * 4];
        xb[(size_t)i * 2 + 0] = pack2(v.x, v.y);
        xb[(size_t)i * 2 + 1] = pack2(v.z, v.w);
    } else {
        const int i = (b - 15000) * 256 + threadIdx.x;    // < 49,152 exact
        if (i < 128 * 256) {
            const int k = i >> 8, n = i & 255;
            W1t[n * 128 + k] = f2b(W1[i]);
        } else {
            const int j = i - 128 * 256;                  // j < 256*64
            const int k = j >> 6, n = j & 63;
            W2t[n * 256 + k] = f2b(W2[j]);
        }
    }
}

// ---------------------------------------------------------------------------
// scanA + dinv fused: per-1024 exclusive scan of cnt -> offs, block sums,
// and dinv[i] = rsqrt(1+cnt[i])
// ---------------------------------------------------------------------------
__global__ __launch_bounds__(256)
void scanA_dinv(const int* __restrict__ cnt, int* __restrict__ offs,
                int* __restrict__ bsum, float* __restrict__ dinv) {
    __shared__ int s[256];
    const int t = threadIdx.x;
    const int base = blockIdx.x * 1024 + t * 4;
    int c0 = (base + 0 < NND) ? cnt[base + 0] : 0;
    int c1 = (base + 1 < NND) ? cnt[base + 1] : 0;
    int c2 = (base + 2 < NND) ? cnt[base + 2] : 0;
    int c3 = (base + 3 < NND) ? cnt[base + 3] : 0;
    if (base + 0 < NND) dinv[base + 0] = rsqrtf(1.0f + (float)c0);
    if (base + 1 < NND) dinv[base + 1] = rsqrtf(1.0f + (float)c1);
    if (base + 2 < NND) dinv[base + 2] = rsqrtf(1.0f + (float)c2);
    if (base + 3 < NND) dinv[base + 3] = rsqrtf(1.0f + (float)c3);
    const int local = c0 + c1 + c2 + c3;
    s[t] = local;
    __syncthreads();
    for (int off = 1; off < 256; off <<= 1) {
        int v = (t >= off) ? s[t - off] : 0;
        __syncthreads();
        s[t] += v;
        __syncthreads();
    }
    const int excl = s[t] - local;
    if (t == 255) bsum[blockIdx.x] = s[255];
    if (base + 0 < NND) offs[base + 0] = excl;
    if (base + 1 < NND) offs[base + 1] = excl + c0;
    if (base + 2 < NND) offs[base + 2] = excl + c0 + c1;
    if (base + 3 < NND) offs[base + 3] = excl + c0 + c1 + c2;
}

// scanC2: each block redundantly prefixes the 98 block sums, then applies;
// cursor (=cnt reused) initialized to final offset.  Removes scanB kernel.
__global__ __launch_bounds__(256)
void scanC2(int* __restrict__ offs, const int* __restrict__ bsum,
            int* __restrict__ cursor) {
    __shared__ int pref[NSCAN_B];
    if (threadIdx.x < NSCAN_B) pref[threadIdx.x] = bsum[threadIdx.x];
    __syncthreads();
    if (threadIdx.x == 0) {
        int run = 0;
        #pragma unroll 1
        for (int b = 0; b < NSCAN_B; ++b) { int v = pref[b]; pref[b] = run; run += v; }
    }
    __syncthreads();
    const int i = blockIdx.x * 256 + threadIdx.x;
    if (i < NND) {
        const int v = offs[i] + pref[i >> 10];
        offs[i] = v;
        cursor[i] = v;
    }
    if (i == 0) offs[NND] = NED;
}

// fill CSR sorted by dst; packed 8B record {src, bits(dinv[src]*dinv[dst])}
__global__ __launch_bounds__(256)
void fill_kernel(const int* __restrict__ ei, const float* __restrict__ dinv,
                 int* __restrict__ cursor, uint2* __restrict__ recS) {
    const int e = blockIdx.x * 256 + threadIdx.x;
    if (e < NED) {
        const int src = ei[e], dst = ei[NED + e];
        const int p = atomicAdd(&cursor[dst], 1);
        recS[p] = make_uint2((u32)src, __float_as_uint(dinv[src] * dinv[dst]));
    }
}

// ---------------------------------------------------------------------------
// CSR gather (bf16), 8-wide predicated edge groups, packed edge records.
// z[d] = dinv[d]^2*x[d] + sum_e wt[e]*x[src[e]]    (one wave per node)
// ---------------------------------------------------------------------------
__global__ __launch_bounds__(256)
void gather128b(const int* __restrict__ offs, const uint2* __restrict__ recS,
                const float* __restrict__ dinv,
                const u32* __restrict__ xb, u32* __restrict__ zb) {
    const int d    = (blockIdx.x * 256 + threadIdx.x) >> 6;
    const int lane = threadIdx.x & 63;
    if (d >= NND) return;
    const int beg = offs[d], end = offs[d + 1];
    const float dd = dinv[d];
    const u32 s = xb[(size_t)d * 64 + lane];
    float ax = b2f((u16)s) * dd * dd;
    float ay = b2f((u16)(s >> 16)) * dd * dd;
    for (int e = beg; e < end; e += 8) {
        uint2 r[8]; float wi[8]; u32 vi[8];
        #pragma unroll
        for (int j = 0; j < 8; ++j) {
            const int ee = e + j;
            r[j] = recS[(ee < end) ? ee : (end - 1)];
        }
        #pragma unroll
        for (int j = 0; j < 8; ++j) {
            wi[j] = (e + j < end) ? __uint_as_float(r[j].y) : 0.0f;
            vi[j] = xb[(size_t)r[j].x * 64 + lane];
        }
        #pragma unroll
        for (int j = 0; j < 8; ++j) {
            ax = fmaf(wi[j], b2f((u16)vi[j]), ax);
            ay = fmaf(wi[j], b2f((u16)(vi[j] >> 16)), ay);
        }
    }
    zb[(size_t)d * 64 + lane] = pack2(ax, ay);
}

// out[d] += sum_e wt[e]*xw2[src[e]]  — TWO nodes per wave (32 lanes x u32/row),
// doubles independent edge streams per wave for MLP.
__global__ __launch_bounds__(256)
void gather64b(const int* __restrict__ offs, const uint2* __restrict__ recS,
               const u32* __restrict__ xw32, float* __restrict__ out) {
    const int t    = blockIdx.x * 256 + threadIdx.x;
    const int d    = t >> 5;
    const int lane = t & 31;
    if (d >= NND) return;
    const int beg = offs[d], end = offs[d + 1];
    float2* p = (float2*)&out[(size_t)d * 64 + lane * 2];
    float2 acc = *p;
    for (int e = beg; e < end; e += 8) {
        uint2 r[8]; float wi[8]; u32 vi[8];
        #pragma unroll
        for (int j = 0; j < 8; ++j) {
            const int ee = e + j;
            r[j] = recS[(ee < end) ? ee : (end - 1)];
        }
        #pragma unroll
        for (int j = 0; j < 8; ++j) {
            wi[j] = (e + j < end) ? __uint_as_float(r[j].y) : 0.0f;
            vi[j] = xw32[(size_t)r[j].x * 32 + lane];
        }
        #pragma unroll
        for (int j = 0; j < 8; ++j) {
            acc.x = fmaf(wi[j], b2f((u16)vi[j]), acc.x);
            acc.y = fmaf(wi[j], b2f((u16)(vi[j] >> 16)), acc.y);
        }
    }
    *p = acc;
}

// ---------------------------------------------------------------------------
// bf16 MFMA GEMM: C = A[M][K] @ Bt[N][K]^T, 4 waves, 64x64 per wave, BK=32.
// EPI 0: O1(bf16) = relu(acc + bias[col])                        (layer-1 h)
// EPI 1: O1(bf16) = acc ; O2(fp32) = dinv[row]^2*acc + bias[col] (xw2 + out-init)
// ---------------------------------------------------------------------------
template<int BM, int BN, int WM, int WN, int EPI>
__global__ __launch_bounds__(256)
void gemm_mfma(const u16* __restrict__ A, const u16* __restrict__ Bt,
               const float* __restrict__ bias, const float* __restrict__ dinv,
               void* __restrict__ O1, float* __restrict__ O2,
               int M, int N, int K)
{
    __shared__ __align__(16) u16 As[BM * 32];
    __shared__ __align__(16) u16 Bs[BN * 32];
    const int tid  = threadIdx.x;
    const int lane = tid & 63;
    const int wid  = tid >> 6;
    const int wm   = wid % WM;
    const int wn   = wid / WM;
    const int row0 = blockIdx.x * BM;
    const int col0 = blockIdx.y * BN;
    const int wrow0 = wm * 64, wcol0 = wn * 64;

    f32x4 acc[4][4];
    #pragma unroll
    for (int i = 0; i < 4; ++i)
        #pragma unroll
        for (int j = 0; j < 4; ++j) acc[i][j] = (f32x4){0.f, 0.f, 0.f, 0.f};

    const int lr = lane >> 2;          // 0..15: row within 16-row load chunk
    const int lk = (lane & 3) * 8;     // k-element offset (16B granule)

    for (int kt = 0; kt < K; kt += 32) {
        #pragma unroll
        for (int j = 0; j < BM / 64; ++j) {
            const int li = wid * (BM / 64) + j;            // 16 rows per load
            const int r  = li * 16 + lr;
            const int rg = (row0 + r < M) ? (row0 + r) : (M - 1);
            gload16(&As[li * 512], &A[(size_t)rg * K + kt + lk]);
        }
        #pragma unroll
        for (int j = 0; j < BN / 64; ++j) {
            const int li = wid * (BN / 64) + j;
            const int n  = li * 16 + lr;
            gload16(&Bs[li * 512], &Bt[(size_t)(col0 + n) * K + kt + lk]);
        }
        __syncthreads();

        bf16x8 af[4], bfr[4];
        #pragma unroll
        for (int mi = 0; mi < 4; ++mi)
            af[mi] = *(const bf16x8*)&As[(wrow0 + mi * 16 + (lane & 15)) * 32 + (lane >> 4) * 8];
        #pragma unroll
        for (int ni = 0; ni < 4; ++ni)
            bfr[ni] = *(const bf16x8*)&Bs[(wcol0 + ni * 16 + (lane & 15)) * 32 + (lane >> 4) * 8];
        #pragma unroll
        for (int mi = 0; mi < 4; ++mi)
            #pragma unroll
            for (int ni = 0; ni < 4; ++ni)
                acc[mi][ni] = __builtin_amdgcn_mfma_f32_16x16x32_bf16(
                    af[mi], bfr[ni], acc[mi][ni], 0, 0, 0);
        __syncthreads();
    }

    const int rb = (lane >> 4) * 4;
    const int cl = lane & 15;
    #pragma unroll
    for (int mi = 0; mi < 4; ++mi) {
        #pragma unroll
        for (int r = 0; r < 4; ++r) {
            const int row = row0 + wrow0 + mi * 16 + rb + r;
            if (row >= M) continue;
            #pragma unroll
            for (int ni = 0; ni < 4; ++ni) {
                const int col = col0 + wcol0 + ni * 16 + cl;
                const float v = acc[mi][ni][r];
                if constexpr (EPI == 0) {
                    ((u16*)O1)[(size_t)row * N + col] = f2b(fmaxf(v + bias[col], 0.f));
                } else {
                    ((u16*)O1)[(size_t)row * N + col] = f2b(v);
                    const float dd = dinv[row];
                    O2[(size_t)row * N + col] = fmaf(dd * dd, v, bias[col]);
                }
            }
        }
    }
}

// ---------------------------------------------------------------------------
extern "C" void kernel_launch(void* const* d_in, const int* in_sizes, int n_in,
                              void* d_out, int out_size, void* d_ws, size_t ws_size,
                              hipStream_t stream)
{
    const float* x  = (const float*)d_in[0];
    const int*   ei = (const int*)d_in[1];   // [2, E]: src row then dst row
    const float* W1 = (const float*)d_in[2];
    const float* b1 = (const float*)d_in[3];
    const float* W2 = (const float*)d_in[4];
    const float* b2 = (const float*)d_in[5];
    float* out = (float*)d_out;

    // workspace layout (bytes, all 128-aligned):
    char* ws = (char*)d_ws;
    float* dinv = (float*)(ws + 0);            //    400,000 -> 400,128
    int*   cnt  = (int*)  (ws + 400128);       //    400,000 -> 800,128 (reused as cursor)
    int*   offs = (int*)  (ws + 800128);       //    400,004 -> 1,200,256
    int*   bsum = (int*)  (ws + 1200256);      //        512 -> 1,200,768
    uint2* recS = (uint2*)(ws + 1200768);      //  5,120,000 -> 6,320,768  (packed src+wt)
    u32*   xb   = (u32*)  (ws + 6320768);      // 25,600,000 -> 31,920,768  (x bf16)
    u32*   zb   = (u32*)  (ws + 31920768);     // 25,600,000 -> 57,520,768  (Ax bf16)
    u16*   hb   = (u16*)  (ws + 57520768);     // 51,200,000 -> 108,720,768 (h bf16)
    u16*   W1t  = (u16*)  (ws + 108720768);    //     65,536 -> 108,786,304
    u16*   W2t  = (u16*)  (ws + 108786304);    //     32,768 -> 108,819,072
    u16*   xwb  = (u16*)  (ws + 108819072);    // 12,800,000 -> 121,619,072 (xw2 bf16)

    // ---- fused pre-pass (deg atomics || x->bf16 || W->bf16^T) ----
    hipMemsetAsync(cnt, 0, NND * sizeof(int), stream);
    fused_pre<<<15192, 256, 0, stream>>>(ei, cnt, x, xb, W1, W2, W1t, W2t);

    // ---- CSR build ----
    scanA_dinv<<<NSCAN_B, 256, 0, stream>>>(cnt, offs, bsum, dinv);
    scanC2<<<(NND + 255) / 256, 256, 0, stream>>>(offs, bsum, cnt);
    fill_kernel<<<(NED + 255) / 256, 256, 0, stream>>>(ei, dinv, cnt, recS);

    // ---- layer 1: z = A~ x  (bf16 gather), h = relu(z@W1 + b1) ----
    gather128b<<<(NND * 64) / 256 + 1, 256, 0, stream>>>(offs, recS, dinv, xb, zb);
    gemm_mfma<128, 128, 2, 2, 0><<<dim3(782, 2), 256, 0, stream>>>(
        (const u16*)zb, W1t, b1, nullptr, hb, nullptr, NND, 256, 128);

    // ---- layer 2: xw2 = h@W2 (bf16), out = dinv^2*xw2 + b2, then gather ----
    gemm_mfma<256, 64, 4, 1, 1><<<dim3(391, 1), 256, 0, stream>>>(
        hb, W2t, b2, dinv, xwb, out, NND, 64, 256);
    gather64b<<<(NND * 32 + 255) / 256, 256, 0, stream>>>(offs, recS, (const u32*)xwb, out);
}

// Round 8
// 196.958 us; speedup vs baseline: 1.1614x; 1.0623x over previous
//
#include <hip/hip_runtime.h>
#include <cstdint>
#include <cstddef>

#define NND 100000
#define NED 640000
#define NSCAN_B 98          // ceil(NND/1024)

typedef unsigned int u32;
typedef unsigned short u16;
typedef __attribute__((ext_vector_type(8))) short bf16x8;
typedef __attribute__((ext_vector_type(4))) float f32x4;

// ---------------------------------------------------------------------------
// helpers: fp32 <-> bf16 (RNE), async global->LDS 16B
// ---------------------------------------------------------------------------
__device__ __forceinline__ u16 f2b(float f) {
    u32 u = __float_as_uint(f);
    return (u16)((u + 0x7fffu + ((u >> 16) & 1u)) >> 16);
}
__device__ __forceinline__ float b2f(u16 b) {
    return __uint_as_float(((u32)b) << 16);
}
__device__ __forceinline__ u32 pack2(float a, float b) {
    return (u32)f2b(a) | ((u32)f2b(b) << 16);
}
__device__ __forceinline__ void gload16(u16* lds, const u16* g) {
    __builtin_amdgcn_global_load_lds(
        (const __attribute__((address_space(1))) u32*)g,
        (__attribute__((address_space(3))) u32*)lds,
        16, 0, 0);
}

// ---------------------------------------------------------------------------
// fused pre-pass: blocks [0,2500) deg atomics ; [2500,15000) cvt x->bf16 ;
// [15000,15192) cvt W1,W2 -> transposed bf16. All independent.
// ---------------------------------------------------------------------------
__global__ __launch_bounds__(256)
void fused_pre(const int* __restrict__ ei, int* __restrict__ cnt,
               const float* __restrict__ x, u32* __restrict__ xb,
               const float* __restrict__ W1, const float* __restrict__ W2,
               u16* __restrict__ W1t, u16* __restrict__ W2t) {
    const int b = blockIdx.x;
    if (b < 2500) {
        const int e = b * 256 + threadIdx.x;              // 2500*256 == NED exact
        atomicAdd(&cnt[ei[NED + e]], 1);
    } else if (b < 15000) {
        const int i = (b - 2500) * 256 + threadIdx.x;     // < 3,200,000 exact
        const float4 v = *(const float4*)&x[(size_t)i * 4];
        xb[(size_t)i * 2 + 0] = pack2(v.x, v.y);
        xb[(size_t)i * 2 + 1] = pack2(v.z, v.w);
    } else {
        const int i = (b - 15000) * 256 + threadIdx.x;    // < 49,152 exact
        if (i < 128 * 256) {
            const int k = i >> 8, n = i & 255;
            W1t[n * 128 + k] = f2b(W1[i]);
        } else {
            const int j = i - 128 * 256;                  // j < 256*64
            const int k = j >> 6, n = j & 63;
            W2t[n * 256 + k] = f2b(W2[j]);
        }
    }
}

// ---------------------------------------------------------------------------
// scanA + dinv fused: per-1024 exclusive scan of cnt -> offs, block sums,
// and dinv[i] = rsqrt(1+cnt[i])
// ---------------------------------------------------------------------------
__global__ __launch_bounds__(256)
void scanA_dinv(const int* __restrict__ cnt, int* __restrict__ offs,
                int* __restrict__ bsum, float* __restrict__ dinv) {
    __shared__ int s[256];
    const int t = threadIdx.x;
    const int base = blockIdx.x * 1024 + t * 4;
    int c0 = (base + 0 < NND) ? cnt[base + 0] : 0;
    int c1 = (base + 1 < NND) ? cnt[base + 1] : 0;
    int c2 = (base + 2 < NND) ? cnt[base + 2] : 0;
    int c3 = (base + 3 < NND) ? cnt[base + 3] : 0;
    if (base + 0 < NND) dinv[base + 0] = rsqrtf(1.0f + (float)c0);
    if (base + 1 < NND) dinv[base + 1] = rsqrtf(1.0f + (float)c1);
    if (base + 2 < NND) dinv[base + 2] = rsqrtf(1.0f + (float)c2);
    if (base + 3 < NND) dinv[base + 3] = rsqrtf(1.0f + (float)c3);
    const int local = c0 + c1 + c2 + c3;
    s[t] = local;
    __syncthreads();
    for (int off = 1; off < 256; off <<= 1) {
        int v = (t >= off) ? s[t - off] : 0;
        __syncthreads();
        s[t] += v;
        __syncthreads();
    }
    const int excl = s[t] - local;
    if (t == 255) bsum[blockIdx.x] = s[255];
    if (base + 0 < NND) offs[base + 0] = excl;
    if (base + 1 < NND) offs[base + 1] = excl + c0;
    if (base + 2 < NND) offs[base + 2] = excl + c0 + c1;
    if (base + 3 < NND) offs[base + 3] = excl + c0 + c1 + c2;
}

// scanC2: each block redundantly prefixes the 98 block sums, then applies;
// cursor (=cnt reused) initialized to final offset.
__global__ __launch_bounds__(256)
void scanC2(int* __restrict__ offs, const int* __restrict__ bsum,
            int* __restrict__ cursor) {
    __shared__ int pref[NSCAN_B];
    if (threadIdx.x < NSCAN_B) pref[threadIdx.x] = bsum[threadIdx.x];
    __syncthreads();
    if (threadIdx.x == 0) {
        int run = 0;
        #pragma unroll 1
        for (int b = 0; b < NSCAN_B; ++b) { int v = pref[b]; pref[b] = run; run += v; }
    }
    __syncthreads();
    const int i = blockIdx.x * 256 + threadIdx.x;
    if (i < NND) {
        const int v = offs[i] + pref[i >> 10];
        offs[i] = v;
        cursor[i] = v;
    }
    if (i == 0) offs[NND] = NED;
}

// fill CSR sorted by dst; packed 8B record {src, bits(dinv[src]*dinv[dst])}
__global__ __launch_bounds__(256)
void fill_kernel(const int* __restrict__ ei, const float* __restrict__ dinv,
                 int* __restrict__ cursor, uint2* __restrict__ recS) {
    const int e = blockIdx.x * 256 + threadIdx.x;
    if (e < NED) {
        const int src = ei[e], dst = ei[NED + e];
        const int p = atomicAdd(&cursor[dst], 1);
        recS[p] = make_uint2((u32)src, __float_as_uint(dinv[src] * dinv[dst]));
    }
}

// ---------------------------------------------------------------------------
// CSR gather (bf16), 8-wide predicated edge groups, packed edge records.
// TWO nodes per wave: 32 lanes x uint2 (8B) = 256B row.  Doubles independent
// edge-chains per wave vs one-node-per-wave; traffic unchanged.
// z[d] = dinv[d]^2*x[d] + sum_e wt[e]*x[src[e]]
// ---------------------------------------------------------------------------
__global__ __launch_bounds__(256)
void gather128b(const int* __restrict__ offs, const uint2* __restrict__ recS,
                const float* __restrict__ dinv,
                const uint2* __restrict__ xb2, uint2* __restrict__ zb2) {
    const int t    = blockIdx.x * 256 + threadIdx.x;
    const int d    = t >> 5;
    const int lane = t & 31;
    if (d >= NND) return;
    const int beg = offs[d], end = offs[d + 1];
    const float dd = dinv[d];
    const uint2 s = xb2[(size_t)d * 32 + lane];
    const float d2 = dd * dd;
    float a0 = b2f((u16)s.x) * d2;
    float a1 = b2f((u16)(s.x >> 16)) * d2;
    float a2 = b2f((u16)s.y) * d2;
    float a3 = b2f((u16)(s.y >> 16)) * d2;
    for (int e = beg; e < end; e += 8) {
        uint2 r[8]; float wi[8]; uint2 vi[8];
        #pragma unroll
        for (int j = 0; j < 8; ++j) {
            const int ee = e + j;
            r[j] = recS[(ee < end) ? ee : (end - 1)];
        }
        #pragma unroll
        for (int j = 0; j < 8; ++j) {
            wi[j] = (e + j < end) ? __uint_as_float(r[j].y) : 0.0f;
            vi[j] = xb2[(size_t)r[j].x * 32 + lane];
        }
        #pragma unroll
        for (int j = 0; j < 8; ++j) {
            a0 = fmaf(wi[j], b2f((u16)vi[j].x), a0);
            a1 = fmaf(wi[j], b2f((u16)(vi[j].x >> 16)), a1);
            a2 = fmaf(wi[j], b2f((u16)vi[j].y), a2);
            a3 = fmaf(wi[j], b2f((u16)(vi[j].y >> 16)), a3);
        }
    }
    zb2[(size_t)d * 32 + lane] = make_uint2(pack2(a0, a1), pack2(a2, a3));
}

// out[d] += sum_e wt[e]*xw2[src[e]] — FOUR nodes per wave (16 lanes x uint2 =
// 128B row; lane owns 4 channels, fp32 accumulate into float4 of out).
__global__ __launch_bounds__(256)
void gather64b(const int* __restrict__ offs, const uint2* __restrict__ recS,
               const uint2* __restrict__ xw2v, float* __restrict__ out) {
    const int t    = blockIdx.x * 256 + threadIdx.x;
    const int d    = t >> 4;
    const int lane = t & 15;
    if (d >= NND) return;
    const int beg = offs[d], end = offs[d + 1];
    float4* p = (float4*)&out[(size_t)d * 64 + lane * 4];
    float4 acc = *p;
    for (int e = beg; e < end; e += 8) {
        uint2 r[8]; float wi[8]; uint2 vi[8];
        #pragma unroll
        for (int j = 0; j < 8; ++j) {
            const int ee = e + j;
            r[j] = recS[(ee < end) ? ee : (end - 1)];
        }
        #pragma unroll
        for (int j = 0; j < 8; ++j) {
            wi[j] = (e + j < end) ? __uint_as_float(r[j].y) : 0.0f;
            vi[j] = xw2v[(size_t)r[j].x * 16 + lane];
        }
        #pragma unroll
        for (int j = 0; j < 8; ++j) {
            acc.x = fmaf(wi[j], b2f((u16)vi[j].x), acc.x);
            acc.y = fmaf(wi[j], b2f((u16)(vi[j].x >> 16)), acc.y);
            acc.z = fmaf(wi[j], b2f((u16)vi[j].y), acc.z);
            acc.w = fmaf(wi[j], b2f((u16)(vi[j].y >> 16)), acc.w);
        }
    }
    *p = acc;
}

// ---------------------------------------------------------------------------
// bf16 MFMA GEMM: C = A[M][K] @ Bt[N][K]^T, 4 waves, 64x64 per wave, BK=32.
// EPI 0: O1(bf16) = relu(acc + bias[col])                        (layer-1 h)
// EPI 1: O1(bf16) = acc ; O2(fp32) = dinv[row]^2*acc + bias[col] (xw2 + out-init)
// ---------------------------------------------------------------------------
template<int BM, int BN, int WM, int WN, int EPI>
__global__ __launch_bounds__(256)
void gemm_mfma(const u16* __restrict__ A, const u16* __restrict__ Bt,
               const float* __restrict__ bias, const float* __restrict__ dinv,
               void* __restrict__ O1, float* __restrict__ O2,
               int M, int N, int K)
{
    __shared__ __align__(16) u16 As[BM * 32];
    __shared__ __align__(16) u16 Bs[BN * 32];
    const int tid  = threadIdx.x;
    const int lane = tid & 63;
    const int wid  = tid >> 6;
    const int wm   = wid % WM;
    const int wn   = wid / WM;
    const int row0 = blockIdx.x * BM;
    const int col0 = blockIdx.y * BN;
    const int wrow0 = wm * 64, wcol0 = wn * 64;

    f32x4 acc[4][4];
    #pragma unroll
    for (int i = 0; i < 4; ++i)
        #pragma unroll
        for (int j = 0; j < 4; ++j) acc[i][j] = (f32x4){0.f, 0.f, 0.f, 0.f};

    const int lr = lane >> 2;          // 0..15: row within 16-row load chunk
    const int lk = (lane & 3) * 8;     // k-element offset (16B granule)

    for (int kt = 0; kt < K; kt += 32) {
        #pragma unroll
        for (int j = 0; j < BM / 64; ++j) {
            const int li = wid * (BM / 64) + j;            // 16 rows per load
            const int r  = li * 16 + lr;
            const int rg = (row0 + r < M) ? (row0 + r) : (M - 1);
            gload16(&As[li * 512], &A[(size_t)rg * K + kt + lk]);
        }
        #pragma unroll
        for (int j = 0; j < BN / 64; ++j) {
            const int li = wid * (BN / 64) + j;
            const int n  = li * 16 + lr;
            gload16(&Bs[li * 512], &Bt[(size_t)(col0 + n) * K + kt + lk]);
        }
        __syncthreads();

        bf16x8 af[4], bfr[4];
        #pragma unroll
        for (int mi = 0; mi < 4; ++mi)
            af[mi] = *(const bf16x8*)&As[(wrow0 + mi * 16 + (lane & 15)) * 32 + (lane >> 4) * 8];
        #pragma unroll
        for (int ni = 0; ni < 4; ++ni)
            bfr[ni] = *(const bf16x8*)&Bs[(wcol0 + ni * 16 + (lane & 15)) * 32 + (lane >> 4) * 8];
        #pragma unroll
        for (int mi = 0; mi < 4; ++mi)
            #pragma unroll
            for (int ni = 0; ni < 4; ++ni)
                acc[mi][ni] = __builtin_amdgcn_mfma_f32_16x16x32_bf16(
                    af[mi], bfr[ni], acc[mi][ni], 0, 0, 0);
        __syncthreads();
    }

    const int rb = (lane >> 4) * 4;
    const int cl = lane & 15;
    #pragma unroll
    for (int mi = 0; mi < 4; ++mi) {
        #pragma unroll
        for (int r = 0; r < 4; ++r) {
            const int row = row0 + wrow0 + mi * 16 + rb + r;
            if (row >= M) continue;
            #pragma unroll
            for (int ni = 0; ni < 4; ++ni) {
                const int col = col0 + wcol0 + ni * 16 + cl;
                const float v = acc[mi][ni][r];
                if constexpr (EPI == 0) {
                    ((u16*)O1)[(size_t)row * N + col] = f2b(fmaxf(v + bias[col], 0.f));
                } else {
                    ((u16*)O1)[(size_t)row * N + col] = f2b(v);
                    const float dd = dinv[row];
                    O2[(size_t)row * N + col] = fmaf(dd * dd, v, bias[col]);
                }
            }
        }
    }
}

// ---------------------------------------------------------------------------
extern "C" void kernel_launch(void* const* d_in, const int* in_sizes, int n_in,
                              void* d_out, int out_size, void* d_ws, size_t ws_size,
                              hipStream_t stream)
{
    const float* x  = (const float*)d_in[0];
    const int*   ei = (const int*)d_in[1];   // [2, E]: src row then dst row
    const float* W1 = (const float*)d_in[2];
    const float* b1 = (const float*)d_in[3];
    const float* W2 = (const float*)d_in[4];
    const float* b2 = (const float*)d_in[5];
    float* out = (float*)d_out;

    // workspace layout (bytes, all 128-aligned):
    char* ws = (char*)d_ws;
    float* dinv = (float*)(ws + 0);            //    400,000 -> 400,128
    int*   cnt  = (int*)  (ws + 400128);       //    400,000 -> 800,128 (reused as cursor)
    int*   offs = (int*)  (ws + 800128);       //    400,004 -> 1,200,256
    int*   bsum = (int*)  (ws + 1200256);      //        512 -> 1,200,768
    uint2* recS = (uint2*)(ws + 1200768);      //  5,120,000 -> 6,320,768  (packed src+wt)
    u32*   xb   = (u32*)  (ws + 6320768);      // 25,600,000 -> 31,920,768  (x bf16)
    u32*   zb   = (u32*)  (ws + 31920768);     // 25,600,000 -> 57,520,768  (Ax bf16)
    u16*   hb   = (u16*)  (ws + 57520768);     // 51,200,000 -> 108,720,768 (h bf16)
    u16*   W1t  = (u16*)  (ws + 108720768);    //     65,536 -> 108,786,304
    u16*   W2t  = (u16*)  (ws + 108786304);    //     32,768 -> 108,819,072
    u16*   xwb  = (u16*)  (ws + 108819072);    // 12,800,000 -> 121,619,072 (xw2 bf16)

    // ---- fused pre-pass (deg atomics || x->bf16 || W->bf16^T) ----
    hipMemsetAsync(cnt, 0, NND * sizeof(int), stream);
    fused_pre<<<15192, 256, 0, stream>>>(ei, cnt, x, xb, W1, W2, W1t, W2t);

    // ---- CSR build ----
    scanA_dinv<<<NSCAN_B, 256, 0, stream>>>(cnt, offs, bsum, dinv);
    scanC2<<<(NND + 255) / 256, 256, 0, stream>>>(offs, bsum, cnt);
    fill_kernel<<<(NED + 255) / 256, 256, 0, stream>>>(ei, dinv, cnt, recS);

    // ---- layer 1: z = A~ x  (bf16 gather, 2 nodes/wave), h = relu(z@W1+b1) ----
    gather128b<<<(NND * 32 + 255) / 256, 256, 0, stream>>>(
        offs, recS, dinv, (const uint2*)xb, (uint2*)zb);
    gemm_mfma<128, 128, 2, 2, 0><<<dim3(782, 2), 256, 0, stream>>>(
        (const u16*)zb, W1t, b1, nullptr, hb, nullptr, NND, 256, 128);

    // ---- layer 2: xw2 = h@W2 (bf16), out = dinv^2*xw2 + b2, then gather ----
    gemm_mfma<256, 64, 4, 1, 1><<<dim3(391, 1), 256, 0, stream>>>(
        hb, W2t, b2, dinv, xwb, out, NND, 64, 256);
    gather64b<<<(NND * 16 + 255) / 256, 256, 0, stream>>>(
        offs, recS, (const uint2*)xwb, out);
}

// Round 9
// 190.119 us; speedup vs baseline: 1.2031x; 1.0360x over previous
//
#include <hip/hip_runtime.h>
#include <cstdint>
#include <cstddef>

#define NND 100000
#define NED 640000
#define NSCAN_B 98          // ceil(NND/1024)

typedef unsigned int u32;
typedef unsigned short u16;
typedef __attribute__((ext_vector_type(8))) short bf16x8;
typedef __attribute__((ext_vector_type(4))) float f32x4;
typedef __attribute__((ext_vector_type(2))) u32 u32x2;
typedef __attribute__((ext_vector_type(4))) u32 u32x4;

// ---------------------------------------------------------------------------
// helpers: fp32 <-> bf16 (RNE), async global->LDS 16B
// ---------------------------------------------------------------------------
__device__ __forceinline__ u16 f2b(float f) {
    u32 u = __float_as_uint(f);
    return (u16)((u + 0x7fffu + ((u >> 16) & 1u)) >> 16);
}
__device__ __forceinline__ float b2f(u16 b) {
    return __uint_as_float(((u32)b) << 16);
}
__device__ __forceinline__ u32 pack2(float a, float b) {
    return (u32)f2b(a) | ((u32)f2b(b) << 16);
}
__device__ __forceinline__ void gload16(u16* lds, const u16* g) {
    __builtin_amdgcn_global_load_lds(
        (const __attribute__((address_space(1))) u32*)g,
        (__attribute__((address_space(3))) u32*)lds,
        16, 0, 0);
}

// ---------------------------------------------------------------------------
// fused pre-pass: blocks [0,2500) deg atomics ; [2500,15000) cvt x->bf16 ;
// [15000,15192) cvt W1,W2 -> transposed bf16. All independent.
// ---------------------------------------------------------------------------
__global__ __launch_bounds__(256)
void fused_pre(const int* __restrict__ ei, int* __restrict__ cnt,
               const float* __restrict__ x, u32* __restrict__ xb,
               const float* __restrict__ W1, const float* __restrict__ W2,
               u16* __restrict__ W1t, u16* __restrict__ W2t) {
    const int b = blockIdx.x;
    if (b < 2500) {
        const int e = b * 256 + threadIdx.x;              // 2500*256 == NED exact
        atomicAdd(&cnt[ei[NED + e]], 1);
    } else if (b < 15000) {
        const int i = (b - 2500) * 256 + threadIdx.x;     // < 3,200,000 exact
        const float4 v = *(const float4*)&x[(size_t)i * 4];
        xb[(size_t)i * 2 + 0] = pack2(v.x, v.y);
        xb[(size_t)i * 2 + 1] = pack2(v.z, v.w);
    } else {
        const int i = (b - 15000) * 256 + threadIdx.x;    // < 49,152 exact
        if (i < 128 * 256) {
            const int k = i >> 8, n = i & 255;
            W1t[n * 128 + k] = f2b(W1[i]);
        } else {
            const int j = i - 128 * 256;                  // j < 256*64
            const int k = j >> 6, n = j & 63;
            W2t[n * 256 + k] = f2b(W2[j]);
        }
    }
}

// ---------------------------------------------------------------------------
// scanA + dinv fused: per-1024 exclusive scan of cnt -> offs, block sums,
// and dinv[i] = rsqrt(1+cnt[i])
// ---------------------------------------------------------------------------
__global__ __launch_bounds__(256)
void scanA_dinv(const int* __restrict__ cnt, int* __restrict__ offs,
                int* __restrict__ bsum, float* __restrict__ dinv) {
    __shared__ int s[256];
    const int t = threadIdx.x;
    const int base = blockIdx.x * 1024 + t * 4;
    int c0 = (base + 0 < NND) ? cnt[base + 0] : 0;
    int c1 = (base + 1 < NND) ? cnt[base + 1] : 0;
    int c2 = (base + 2 < NND) ? cnt[base + 2] : 0;
    int c3 = (base + 3 < NND) ? cnt[base + 3] : 0;
    if (base + 0 < NND) dinv[base + 0] = rsqrtf(1.0f + (float)c0);
    if (base + 1 < NND) dinv[base + 1] = rsqrtf(1.0f + (float)c1);
    if (base + 2 < NND) dinv[base + 2] = rsqrtf(1.0f + (float)c2);
    if (base + 3 < NND) dinv[base + 3] = rsqrtf(1.0f + (float)c3);
    const int local = c0 + c1 + c2 + c3;
    s[t] = local;
    __syncthreads();
    for (int off = 1; off < 256; off <<= 1) {
        int v = (t >= off) ? s[t - off] : 0;
        __syncthreads();
        s[t] += v;
        __syncthreads();
    }
    const int excl = s[t] - local;
    if (t == 255) bsum[blockIdx.x] = s[255];
    if (base + 0 < NND) offs[base + 0] = excl;
    if (base + 1 < NND) offs[base + 1] = excl + c0;
    if (base + 2 < NND) offs[base + 2] = excl + c0 + c1;
    if (base + 3 < NND) offs[base + 3] = excl + c0 + c1 + c2;
}

// scanC2: each block redundantly prefixes the 98 block sums, then applies;
// cursor (=cnt reused) initialized to final offset.
__global__ __launch_bounds__(256)
void scanC2(int* __restrict__ offs, const int* __restrict__ bsum,
            int* __restrict__ cursor) {
    __shared__ int pref[NSCAN_B];
    if (threadIdx.x < NSCAN_B) pref[threadIdx.x] = bsum[threadIdx.x];
    __syncthreads();
    if (threadIdx.x == 0) {
        int run = 0;
        #pragma unroll 1
        for (int b = 0; b < NSCAN_B; ++b) { int v = pref[b]; pref[b] = run; run += v; }
    }
    __syncthreads();
    const int i = blockIdx.x * 256 + threadIdx.x;
    if (i < NND) {
        const int v = offs[i] + pref[i >> 10];
        offs[i] = v;
        cursor[i] = v;
    }
    if (i == 0) offs[NND] = NED;
}

// fill CSR sorted by dst; packed 8B record {src, bits(dinv[src]*dinv[dst])},
// written non-temporally (streamed once, keep L2 clean).
__global__ __launch_bounds__(256)
void fill_kernel(const int* __restrict__ ei, const float* __restrict__ dinv,
                 int* __restrict__ cursor, u32x2* __restrict__ recS) {
    const int e = blockIdx.x * 256 + threadIdx.x;
    if (e < NED) {
        const int src = ei[e], dst = ei[NED + e];
        const int p = atomicAdd(&cursor[dst], 1);
        u32x2 rec = {(u32)src, __float_as_uint(dinv[src] * dinv[dst])};
        __builtin_nontemporal_store(rec, &recS[p]);
    }
}

// ---------------------------------------------------------------------------
// CSR gather (bf16), 8-wide predicated edge groups, packed edge records.
// FOUR nodes per wave: 16 lanes x u32x4 (16B) = 256B row.
// z[d] = dinv[d]^2*x[d] + sum_e wt[e]*x[src[e]]
// ---------------------------------------------------------------------------
__global__ __launch_bounds__(256)
void gather128b(const int* __restrict__ offs, const u32x2* __restrict__ recS,
                const float* __restrict__ dinv,
                const u32x4* __restrict__ xb4, u32x4* __restrict__ zb4) {
    const int t    = blockIdx.x * 256 + threadIdx.x;
    const int d    = t >> 4;
    const int lane = t & 15;
    if (d >= NND) return;
    const int beg = offs[d], end = offs[d + 1];
    const float dd = dinv[d];
    const u32x4 s = xb4[(size_t)d * 16 + lane];
    const float d2 = dd * dd;
    float a0 = b2f((u16)s.x) * d2, a1 = b2f((u16)(s.x >> 16)) * d2;
    float a2 = b2f((u16)s.y) * d2, a3 = b2f((u16)(s.y >> 16)) * d2;
    float a4 = b2f((u16)s.z) * d2, a5 = b2f((u16)(s.z >> 16)) * d2;
    float a6 = b2f((u16)s.w) * d2, a7 = b2f((u16)(s.w >> 16)) * d2;
    for (int e = beg; e < end; e += 8) {
        u32x2 r[8]; float wi[8]; u32x4 vi[8];
        #pragma unroll
        for (int j = 0; j < 8; ++j) {
            const int ee = e + j;
            r[j] = __builtin_nontemporal_load(&recS[(ee < end) ? ee : (end - 1)]);
        }
        #pragma unroll
        for (int j = 0; j < 8; ++j) {
            wi[j] = (e + j < end) ? __uint_as_float(r[j].y) : 0.0f;
            vi[j] = xb4[(size_t)r[j].x * 16 + lane];
        }
        #pragma unroll
        for (int j = 0; j < 8; ++j) {
            a0 = fmaf(wi[j], b2f((u16)vi[j].x), a0);
            a1 = fmaf(wi[j], b2f((u16)(vi[j].x >> 16)), a1);
            a2 = fmaf(wi[j], b2f((u16)vi[j].y), a2);
            a3 = fmaf(wi[j], b2f((u16)(vi[j].y >> 16)), a3);
            a4 = fmaf(wi[j], b2f((u16)vi[j].z), a4);
            a5 = fmaf(wi[j], b2f((u16)(vi[j].z >> 16)), a5);
            a6 = fmaf(wi[j], b2f((u16)vi[j].w), a6);
            a7 = fmaf(wi[j], b2f((u16)(vi[j].w >> 16)), a7);
        }
    }
    u32x4 o = {pack2(a0, a1), pack2(a2, a3), pack2(a4, a5), pack2(a6, a7)};
    zb4[(size_t)d * 16 + lane] = o;
}

// out[d] = b2 + dinv[d]^2*xw2[d] + sum_e wt[e]*xw2[src[e]]
// EIGHT nodes per wave: 8 lanes x u32x4 (16B) = 128B row. WRITE-ONLY out.
__global__ __launch_bounds__(256)
void gather64b(const int* __restrict__ offs, const u32x2* __restrict__ recS,
               const float* __restrict__ dinv, const u32x4* __restrict__ xw4,
               const float* __restrict__ b2, float* __restrict__ out) {
    const int t    = blockIdx.x * 256 + threadIdx.x;
    const int d    = t >> 3;
    const int lane = t & 7;
    if (d >= NND) return;
    const int beg = offs[d], end = offs[d + 1];
    const float dd = dinv[d];
    const float d2 = dd * dd;
    const u32x4 s = xw4[(size_t)d * 8 + lane];
    const float4 bl = *(const float4*)&b2[lane * 8];
    const float4 bh = *(const float4*)&b2[lane * 8 + 4];
    float a0 = fmaf(d2, b2f((u16)s.x), bl.x), a1 = fmaf(d2, b2f((u16)(s.x >> 16)), bl.y);
    float a2 = fmaf(d2, b2f((u16)s.y), bl.z), a3 = fmaf(d2, b2f((u16)(s.y >> 16)), bl.w);
    float a4 = fmaf(d2, b2f((u16)s.z), bh.x), a5 = fmaf(d2, b2f((u16)(s.z >> 16)), bh.y);
    float a6 = fmaf(d2, b2f((u16)s.w), bh.z), a7 = fmaf(d2, b2f((u16)(s.w >> 16)), bh.w);
    for (int e = beg; e < end; e += 8) {
        u32x2 r[8]; float wi[8]; u32x4 vi[8];
        #pragma unroll
        for (int j = 0; j < 8; ++j) {
            const int ee = e + j;
            r[j] = __builtin_nontemporal_load(&recS[(ee < end) ? ee : (end - 1)]);
        }
        #pragma unroll
        for (int j = 0; j < 8; ++j) {
            wi[j] = (e + j < end) ? __uint_as_float(r[j].y) : 0.0f;
            vi[j] = xw4[(size_t)r[j].x * 8 + lane];
        }
        #pragma unroll
        for (int j = 0; j < 8; ++j) {
            a0 = fmaf(wi[j], b2f((u16)vi[j].x), a0);
            a1 = fmaf(wi[j], b2f((u16)(vi[j].x >> 16)), a1);
            a2 = fmaf(wi[j], b2f((u16)vi[j].y), a2);
            a3 = fmaf(wi[j], b2f((u16)(vi[j].y >> 16)), a3);
            a4 = fmaf(wi[j], b2f((u16)vi[j].z), a4);
            a5 = fmaf(wi[j], b2f((u16)(vi[j].z >> 16)), a5);
            a6 = fmaf(wi[j], b2f((u16)vi[j].w), a6);
            a7 = fmaf(wi[j], b2f((u16)(vi[j].w >> 16)), a7);
        }
    }
    float* p = &out[(size_t)d * 64 + lane * 8];
    *(float4*)(p + 0) = make_float4(a0, a1, a2, a3);
    *(float4*)(p + 4) = make_float4(a4, a5, a6, a7);
}

// ---------------------------------------------------------------------------
// bf16 MFMA GEMM: C = A[M][K] @ Bt[N][K]^T, 4 waves, 64x64 per wave, BK=32.
// EPI 0: O1(bf16) = relu(acc + bias[col])   (layer-1 h)
// EPI 1: O1(bf16) = acc                      (layer-2 xw2; self+bias in gather)
// ---------------------------------------------------------------------------
template<int BM, int BN, int WM, int WN, int EPI>
__global__ __launch_bounds__(256)
void gemm_mfma(const u16* __restrict__ A, const u16* __restrict__ Bt,
               const float* __restrict__ bias,
               void* __restrict__ O1,
               int M, int N, int K)
{
    __shared__ __align__(16) u16 As[BM * 32];
    __shared__ __align__(16) u16 Bs[BN * 32];
    const int tid  = threadIdx.x;
    const int lane = tid & 63;
    const int wid  = tid >> 6;
    const int wm   = wid % WM;
    const int wn   = wid / WM;
    const int row0 = blockIdx.x * BM;
    const int col0 = blockIdx.y * BN;
    const int wrow0 = wm * 64, wcol0 = wn * 64;

    f32x4 acc[4][4];
    #pragma unroll
    for (int i = 0; i < 4; ++i)
        #pragma unroll
        for (int j = 0; j < 4; ++j) acc[i][j] = (f32x4){0.f, 0.f, 0.f, 0.f};

    const int lr = lane >> 2;          // 0..15: row within 16-row load chunk
    const int lk = (lane & 3) * 8;     // k-element offset (16B granule)

    for (int kt = 0; kt < K; kt += 32) {
        #pragma unroll
        for (int j = 0; j < BM / 64; ++j) {
            const int li = wid * (BM / 64) + j;            // 16 rows per load
            const int r  = li * 16 + lr;
            const int rg = (row0 + r < M) ? (row0 + r) : (M - 1);
            gload16(&As[li * 512], &A[(size_t)rg * K + kt + lk]);
        }
        #pragma unroll
        for (int j = 0; j < BN / 64; ++j) {
            const int li = wid * (BN / 64) + j;
            const int n  = li * 16 + lr;
            gload16(&Bs[li * 512], &Bt[(size_t)(col0 + n) * K + kt + lk]);
        }
        __syncthreads();

        bf16x8 af[4], bfr[4];
        #pragma unroll
        for (int mi = 0; mi < 4; ++mi)
            af[mi] = *(const bf16x8*)&As[(wrow0 + mi * 16 + (lane & 15)) * 32 + (lane >> 4) * 8];
        #pragma unroll
        for (int ni = 0; ni < 4; ++ni)
            bfr[ni] = *(const bf16x8*)&Bs[(wcol0 + ni * 16 + (lane & 15)) * 32 + (lane >> 4) * 8];
        #pragma unroll
        for (int mi = 0; mi < 4; ++mi)
            #pragma unroll
            for (int ni = 0; ni < 4; ++ni)
                acc[mi][ni] = __builtin_amdgcn_mfma_f32_16x16x32_bf16(
                    af[mi], bfr[ni], acc[mi][ni], 0, 0, 0);
        __syncthreads();
    }

    const int rb = (lane >> 4) * 4;
    const int cl = lane & 15;
    #pragma unroll
    for (int mi = 0; mi < 4; ++mi) {
        #pragma unroll
        for (int r = 0; r < 4; ++r) {
            const int row = row0 + wrow0 + mi * 16 + rb + r;
            if (row >= M) continue;
            #pragma unroll
            for (int ni = 0; ni < 4; ++ni) {
                const int col = col0 + wcol0 + ni * 16 + cl;
                const float v = acc[mi][ni][r];
                if constexpr (EPI == 0) {
                    ((u16*)O1)[(size_t)row * N + col] = f2b(fmaxf(v + bias[col], 0.f));
                } else {
                    ((u16*)O1)[(size_t)row * N + col] = f2b(v);
                }
            }
        }
    }
}

// ---------------------------------------------------------------------------
extern "C" void kernel_launch(void* const* d_in, const int* in_sizes, int n_in,
                              void* d_out, int out_size, void* d_ws, size_t ws_size,
                              hipStream_t stream)
{
    const float* x  = (const float*)d_in[0];
    const int*   ei = (const int*)d_in[1];   // [2, E]: src row then dst row
    const float* W1 = (const float*)d_in[2];
    const float* b1 = (const float*)d_in[3];
    const float* W2 = (const float*)d_in[4];
    const float* b2 = (const float*)d_in[5];
    float* out = (float*)d_out;

    // workspace layout (bytes, all 128-aligned):
    char* ws = (char*)d_ws;
    float* dinv = (float*)(ws + 0);            //    400,000 -> 400,128
    int*   cnt  = (int*)  (ws + 400128);       //    400,000 -> 800,128 (reused as cursor)
    int*   offs = (int*)  (ws + 800128);       //    400,004 -> 1,200,256
    int*   bsum = (int*)  (ws + 1200256);      //        512 -> 1,200,768
    u32x2* recS = (u32x2*)(ws + 1200768);      //  5,120,000 -> 6,320,768  (packed src+wt)
    u32*   xb   = (u32*)  (ws + 6320768);      // 25,600,000 -> 31,920,768  (x bf16)
    u32*   zb   = (u32*)  (ws + 31920768);     // 25,600,000 -> 57,520,768  (Ax bf16)
    u16*   hb   = (u16*)  (ws + 57520768);     // 51,200,000 -> 108,720,768 (h bf16)
    u16*   W1t  = (u16*)  (ws + 108720768);    //     65,536 -> 108,786,304
    u16*   W2t  = (u16*)  (ws + 108786304);    //     32,768 -> 108,819,072
    u16*   xwb  = (u16*)  (ws + 108819072);    // 12,800,000 -> 121,619,072 (xw2 bf16)

    // ---- fused pre-pass (deg atomics || x->bf16 || W->bf16^T) ----
    hipMemsetAsync(cnt, 0, NND * sizeof(int), stream);
    fused_pre<<<15192, 256, 0, stream>>>(ei, cnt, x, xb, W1, W2, W1t, W2t);

    // ---- CSR build ----
    scanA_dinv<<<NSCAN_B, 256, 0, stream>>>(cnt, offs, bsum, dinv);
    scanC2<<<(NND + 255) / 256, 256, 0, stream>>>(offs, bsum, cnt);
    fill_kernel<<<(NED + 255) / 256, 256, 0, stream>>>(ei, dinv, cnt, recS);

    // ---- layer 1: z = A~ x (bf16 gather, 4 nodes/wave), h = relu(z@W1+b1) ----
    gather128b<<<(NND * 16 + 255) / 256, 256, 0, stream>>>(
        offs, recS, dinv, (const u32x4*)xb, (u32x4*)zb);
    gemm_mfma<128, 128, 2, 2, 0><<<dim3(782, 2), 256, 0, stream>>>(
        (const u16*)zb, W1t, b1, hb, NND, 256, 128);

    // ---- layer 2: xw2 = h@W2 (bf16); out = b2 + dinv^2*xw2 + gather (8/wave) ----
    gemm_mfma<256, 64, 4, 1, 1><<<dim3(391, 1), 256, 0, stream>>>(
        hb, W2t, nullptr, xwb, NND, 64, 256);
    gather64b<<<(NND * 8 + 255) / 256, 256, 0, stream>>>(
        offs, recS, dinv, (const u32x4*)xwb, b2, out);
}

// Round 10
// 189.296 us; speedup vs baseline: 1.2084x; 1.0043x over previous
//
#include <hip/hip_runtime.h>
#include <cstdint>
#include <cstddef>

#define NND 100000
#define NED 640000
#define NSCAN_B 98          // ceil(NND/1024)
#define NPART 8             // dst-space partitions (== XCDs)
#define PSZ 12500           // NND / NPART
#define NCHUNK 313          // ceil(NED/2048)

typedef unsigned int u32;
typedef unsigned short u16;
typedef __attribute__((ext_vector_type(8))) short bf16x8;
typedef __attribute__((ext_vector_type(4))) float f32x4;
typedef __attribute__((ext_vector_type(2))) u32 u32x2;
typedef __attribute__((ext_vector_type(4))) u32 u32x4;

// ---------------------------------------------------------------------------
// helpers: fp32 <-> bf16 (RNE), async global->LDS 16B
// ---------------------------------------------------------------------------
__device__ __forceinline__ u16 f2b(float f) {
    u32 u = __float_as_uint(f);
    return (u16)((u + 0x7fffu + ((u >> 16) & 1u)) >> 16);
}
__device__ __forceinline__ float b2f(u16 b) {
    return __uint_as_float(((u32)b) << 16);
}
__device__ __forceinline__ u32 pack2(float a, float b) {
    return (u32)f2b(a) | ((u32)f2b(b) << 16);
}
__device__ __forceinline__ void gload16(u16* lds, const u16* g) {
    __builtin_amdgcn_global_load_lds(
        (const __attribute__((address_space(1))) u32*)g,
        (__attribute__((address_space(3))) u32*)lds,
        16, 0, 0);
}

// ---------------------------------------------------------------------------
// fused pre-pass:
//   blocks [0, 2504): dst-PARTITIONED deg atomics — block b handles partition
//     (b&7) over edge chunk (b>>3); only its XCD touches cnt[p-range] -> L2-local.
//   blocks [2504, 15004): cvt x->bf16
//   blocks [15004, 15196): cvt W1,W2 -> transposed bf16
// ---------------------------------------------------------------------------
__global__ __launch_bounds__(256)
void fused_pre(const int* __restrict__ ei, int* __restrict__ cnt,
               const float* __restrict__ x, u32* __restrict__ xb,
               const float* __restrict__ W1, const float* __restrict__ W2,
               u16* __restrict__ W1t, u16* __restrict__ W2t) {
    const int b = blockIdx.x;
    if (b < NPART * NCHUNK) {
        const int part = b & 7, chunk = b >> 3;
        const int lo = part * PSZ, hi = lo + PSZ;
        const int e0 = chunk * 2048 + threadIdx.x * 8;
        if (e0 < NED) {
            const int4 d0 = *(const int4*)&ei[NED + e0];
            const int4 d1 = *(const int4*)&ei[NED + e0 + 4];
            const int dv[8] = {d0.x, d0.y, d0.z, d0.w, d1.x, d1.y, d1.z, d1.w};
            #pragma unroll
            for (int j = 0; j < 8; ++j)
                if (dv[j] >= lo && dv[j] < hi) atomicAdd(&cnt[dv[j]], 1);
        }
    } else if (b < 2504 + 12500) {
        const int i = (b - 2504) * 256 + threadIdx.x;     // < 3,200,000 exact
        const float4 v = *(const float4*)&x[(size_t)i * 4];
        xb[(size_t)i * 2 + 0] = pack2(v.x, v.y);
        xb[(size_t)i * 2 + 1] = pack2(v.z, v.w);
    } else {
        const int i = (b - 15004) * 256 + threadIdx.x;    // < 49,152 exact
        if (i < 128 * 256) {
            const int k = i >> 8, n = i & 255;
            W1t[n * 128 + k] = f2b(W1[i]);
        } else {
            const int j = i - 128 * 256;                  // j < 256*64
            const int k = j >> 6, n = j & 63;
            W2t[n * 256 + k] = f2b(W2[j]);
        }
    }
}

// ---------------------------------------------------------------------------
// scanA + dinv fused: per-1024 exclusive scan of cnt -> offs, block sums,
// and dinv[i] = rsqrt(1+cnt[i])
// ---------------------------------------------------------------------------
__global__ __launch_bounds__(256)
void scanA_dinv(const int* __restrict__ cnt, int* __restrict__ offs,
                int* __restrict__ bsum, float* __restrict__ dinv) {
    __shared__ int s[256];
    const int t = threadIdx.x;
    const int base = blockIdx.x * 1024 + t * 4;
    int c0 = (base + 0 < NND) ? cnt[base + 0] : 0;
    int c1 = (base + 1 < NND) ? cnt[base + 1] : 0;
    int c2 = (base + 2 < NND) ? cnt[base + 2] : 0;
    int c3 = (base + 3 < NND) ? cnt[base + 3] : 0;
    if (base + 0 < NND) dinv[base + 0] = rsqrtf(1.0f + (float)c0);
    if (base + 1 < NND) dinv[base + 1] = rsqrtf(1.0f + (float)c1);
    if (base + 2 < NND) dinv[base + 2] = rsqrtf(1.0f + (float)c2);
    if (base + 3 < NND) dinv[base + 3] = rsqrtf(1.0f + (float)c3);
    const int local = c0 + c1 + c2 + c3;
    s[t] = local;
    __syncthreads();
    for (int off = 1; off < 256; off <<= 1) {
        int v = (t >= off) ? s[t - off] : 0;
        __syncthreads();
        s[t] += v;
        __syncthreads();
    }
    const int excl = s[t] - local;
    if (t == 255) bsum[blockIdx.x] = s[255];
    if (base + 0 < NND) offs[base + 0] = excl;
    if (base + 1 < NND) offs[base + 1] = excl + c0;
    if (base + 2 < NND) offs[base + 2] = excl + c0 + c1;
    if (base + 3 < NND) offs[base + 3] = excl + c0 + c1 + c2;
}

// scanC2: each block redundantly prefixes the 98 block sums, then applies;
// cursor (=cnt reused) initialized to final offset.
__global__ __launch_bounds__(256)
void scanC2(int* __restrict__ offs, const int* __restrict__ bsum,
            int* __restrict__ cursor) {
    __shared__ int pref[NSCAN_B];
    if (threadIdx.x < NSCAN_B) pref[threadIdx.x] = bsum[threadIdx.x];
    __syncthreads();
    if (threadIdx.x == 0) {
        int run = 0;
        #pragma unroll 1
        for (int b = 0; b < NSCAN_B; ++b) { int v = pref[b]; pref[b] = run; run += v; }
    }
    __syncthreads();
    const int i = blockIdx.x * 256 + threadIdx.x;
    if (i < NND) {
        const int v = offs[i] + pref[i >> 10];
        offs[i] = v;
        cursor[i] = v;
    }
    if (i == 0) offs[NND] = NED;
}

// ---------------------------------------------------------------------------
// dst-PARTITIONED CSR fill: block b = (partition b&7, edge chunk b>>3).
// Only partition p's blocks (on XCD p) touch cursor[p-range] and the
// contiguous recS region for that dst range (~640KB, L2-resident) ->
// each record line accumulates all 8 records and is written back ONCE.
// ---------------------------------------------------------------------------
__global__ __launch_bounds__(256)
void fill_part(const int* __restrict__ ei, const float* __restrict__ dinv,
               int* __restrict__ cursor, u32x2* __restrict__ recS) {
    const int b = blockIdx.x;
    const int part = b & 7, chunk = b >> 3;
    const int lo = part * PSZ, hi = lo + PSZ;
    const int e0 = chunk * 2048 + threadIdx.x * 8;
    if (e0 >= NED) return;
    const int4 s0 = *(const int4*)&ei[e0];
    const int4 s1 = *(const int4*)&ei[e0 + 4];
    const int4 d0 = *(const int4*)&ei[NED + e0];
    const int4 d1 = *(const int4*)&ei[NED + e0 + 4];
    const int sv[8] = {s0.x, s0.y, s0.z, s0.w, s1.x, s1.y, s1.z, s1.w};
    const int dv[8] = {d0.x, d0.y, d0.z, d0.w, d1.x, d1.y, d1.z, d1.w};
    #pragma unroll
    for (int j = 0; j < 8; ++j) {
        if (dv[j] >= lo && dv[j] < hi) {
            const int p = atomicAdd(&cursor[dv[j]], 1);
            u32x2 rec = {(u32)sv[j], __float_as_uint(dinv[sv[j]] * dinv[dv[j]])};
            recS[p] = rec;
        }
    }
}

// ---------------------------------------------------------------------------
// CSR gather (bf16), 8-wide predicated edge groups, packed edge records.
// FOUR nodes per wave: 16 lanes x u32x4 (16B) = 256B row.
// z[d] = dinv[d]^2*x[d] + sum_e wt[e]*x[src[e]]
// ---------------------------------------------------------------------------
__global__ __launch_bounds__(256)
void gather128b(const int* __restrict__ offs, const u32x2* __restrict__ recS,
                const float* __restrict__ dinv,
                const u32x4* __restrict__ xb4, u32x4* __restrict__ zb4) {
    const int t    = blockIdx.x * 256 + threadIdx.x;
    const int d    = t >> 4;
    const int lane = t & 15;
    if (d >= NND) return;
    const int beg = offs[d], end = offs[d + 1];
    const float dd = dinv[d];
    const u32x4 s = xb4[(size_t)d * 16 + lane];
    const float d2 = dd * dd;
    float a0 = b2f((u16)s.x) * d2, a1 = b2f((u16)(s.x >> 16)) * d2;
    float a2 = b2f((u16)s.y) * d2, a3 = b2f((u16)(s.y >> 16)) * d2;
    float a4 = b2f((u16)s.z) * d2, a5 = b2f((u16)(s.z >> 16)) * d2;
    float a6 = b2f((u16)s.w) * d2, a7 = b2f((u16)(s.w >> 16)) * d2;
    for (int e = beg; e < end; e += 8) {
        u32x2 r[8]; float wi[8]; u32x4 vi[8];
        #pragma unroll
        for (int j = 0; j < 8; ++j) {
            const int ee = e + j;
            r[j] = __builtin_nontemporal_load(&recS[(ee < end) ? ee : (end - 1)]);
        }
        #pragma unroll
        for (int j = 0; j < 8; ++j) {
            wi[j] = (e + j < end) ? __uint_as_float(r[j].y) : 0.0f;
            vi[j] = xb4[(size_t)r[j].x * 16 + lane];
        }
        #pragma unroll
        for (int j = 0; j < 8; ++j) {
            a0 = fmaf(wi[j], b2f((u16)vi[j].x), a0);
            a1 = fmaf(wi[j], b2f((u16)(vi[j].x >> 16)), a1);
            a2 = fmaf(wi[j], b2f((u16)vi[j].y), a2);
            a3 = fmaf(wi[j], b2f((u16)(vi[j].y >> 16)), a3);
            a4 = fmaf(wi[j], b2f((u16)vi[j].z), a4);
            a5 = fmaf(wi[j], b2f((u16)(vi[j].z >> 16)), a5);
            a6 = fmaf(wi[j], b2f((u16)vi[j].w), a6);
            a7 = fmaf(wi[j], b2f((u16)(vi[j].w >> 16)), a7);
        }
    }
    u32x4 o = {pack2(a0, a1), pack2(a2, a3), pack2(a4, a5), pack2(a6, a7)};
    zb4[(size_t)d * 16 + lane] = o;
}

// out[d] = b2 + dinv[d]^2*xw2[d] + sum_e wt[e]*xw2[src[e]]
// EIGHT nodes per wave: 8 lanes x u32x4 (16B) = 128B row. WRITE-ONLY out.
__global__ __launch_bounds__(256)
void gather64b(const int* __restrict__ offs, const u32x2* __restrict__ recS,
               const float* __restrict__ dinv, const u32x4* __restrict__ xw4,
               const float* __restrict__ b2, float* __restrict__ out) {
    const int t    = blockIdx.x * 256 + threadIdx.x;
    const int d    = t >> 3;
    const int lane = t & 7;
    if (d >= NND) return;
    const int beg = offs[d], end = offs[d + 1];
    const float dd = dinv[d];
    const float d2 = dd * dd;
    const u32x4 s = xw4[(size_t)d * 8 + lane];
    const float4 bl = *(const float4*)&b2[lane * 8];
    const float4 bh = *(const float4*)&b2[lane * 8 + 4];
    float a0 = fmaf(d2, b2f((u16)s.x), bl.x), a1 = fmaf(d2, b2f((u16)(s.x >> 16)), bl.y);
    float a2 = fmaf(d2, b2f((u16)s.y), bl.z), a3 = fmaf(d2, b2f((u16)(s.y >> 16)), bl.w);
    float a4 = fmaf(d2, b2f((u16)s.z), bh.x), a5 = fmaf(d2, b2f((u16)(s.z >> 16)), bh.y);
    float a6 = fmaf(d2, b2f((u16)s.w), bh.z), a7 = fmaf(d2, b2f((u16)(s.w >> 16)), bh.w);
    for (int e = beg; e < end; e += 8) {
        u32x2 r[8]; float wi[8]; u32x4 vi[8];
        #pragma unroll
        for (int j = 0; j < 8; ++j) {
            const int ee = e + j;
            r[j] = __builtin_nontemporal_load(&recS[(ee < end) ? ee : (end - 1)]);
        }
        #pragma unroll
        for (int j = 0; j < 8; ++j) {
            wi[j] = (e + j < end) ? __uint_as_float(r[j].y) : 0.0f;
            vi[j] = xw4[(size_t)r[j].x * 8 + lane];
        }
        #pragma unroll
        for (int j = 0; j < 8; ++j) {
            a0 = fmaf(wi[j], b2f((u16)vi[j].x), a0);
            a1 = fmaf(wi[j], b2f((u16)(vi[j].x >> 16)), a1);
            a2 = fmaf(wi[j], b2f((u16)vi[j].y), a2);
            a3 = fmaf(wi[j], b2f((u16)(vi[j].y >> 16)), a3);
            a4 = fmaf(wi[j], b2f((u16)vi[j].z), a4);
            a5 = fmaf(wi[j], b2f((u16)(vi[j].z >> 16)), a5);
            a6 = fmaf(wi[j], b2f((u16)vi[j].w), a6);
            a7 = fmaf(wi[j], b2f((u16)(vi[j].w >> 16)), a7);
        }
    }
    float* p = &out[(size_t)d * 64 + lane * 8];
    *(float4*)(p + 0) = make_float4(a0, a1, a2, a3);
    *(float4*)(p + 4) = make_float4(a4, a5, a6, a7);
}

// ---------------------------------------------------------------------------
// bf16 MFMA GEMM: C = A[M][K] @ Bt[N][K]^T, 4 waves, 64x64 per wave, BK=32.
// EPI 0: O1(bf16) = relu(acc + bias[col])   (layer-1 h)
// EPI 1: O1(bf16) = acc                      (layer-2 xw2; self+bias in gather)
// ---------------------------------------------------------------------------
template<int BM, int BN, int WM, int WN, int EPI>
__global__ __launch_bounds__(256)
void gemm_mfma(const u16* __restrict__ A, const u16* __restrict__ Bt,
               const float* __restrict__ bias,
               void* __restrict__ O1,
               int M, int N, int K)
{
    __shared__ __align__(16) u16 As[BM * 32];
    __shared__ __align__(16) u16 Bs[BN * 32];
    const int tid  = threadIdx.x;
    const int lane = tid & 63;
    const int wid  = tid >> 6;
    const int wm   = wid % WM;
    const int wn   = wid / WM;
    const int row0 = blockIdx.x * BM;
    const int col0 = blockIdx.y * BN;
    const int wrow0 = wm * 64, wcol0 = wn * 64;

    f32x4 acc[4][4];
    #pragma unroll
    for (int i = 0; i < 4; ++i)
        #pragma unroll
        for (int j = 0; j < 4; ++j) acc[i][j] = (f32x4){0.f, 0.f, 0.f, 0.f};

    const int lr = lane >> 2;          // 0..15: row within 16-row load chunk
    const int lk = (lane & 3) * 8;     // k-element offset (16B granule)

    for (int kt = 0; kt < K; kt += 32) {
        #pragma unroll
        for (int j = 0; j < BM / 64; ++j) {
            const int li = wid * (BM / 64) + j;            // 16 rows per load
            const int r  = li * 16 + lr;
            const int rg = (row0 + r < M) ? (row0 + r) : (M - 1);
            gload16(&As[li * 512], &A[(size_t)rg * K + kt + lk]);
        }
        #pragma unroll
        for (int j = 0; j < BN / 64; ++j) {
            const int li = wid * (BN / 64) + j;
            const int n  = li * 16 + lr;
            gload16(&Bs[li * 512], &Bt[(size_t)(col0 + n) * K + kt + lk]);
        }
        __syncthreads();

        bf16x8 af[4], bfr[4];
        #pragma unroll
        for (int mi = 0; mi < 4; ++mi)
            af[mi] = *(const bf16x8*)&As[(wrow0 + mi * 16 + (lane & 15)) * 32 + (lane >> 4) * 8];
        #pragma unroll
        for (int ni = 0; ni < 4; ++ni)
            bfr[ni] = *(const bf16x8*)&Bs[(wcol0 + ni * 16 + (lane & 15)) * 32 + (lane >> 4) * 8];
        #pragma unroll
        for (int mi = 0; mi < 4; ++mi)
            #pragma unroll
            for (int ni = 0; ni < 4; ++ni)
                acc[mi][ni] = __builtin_amdgcn_mfma_f32_16x16x32_bf16(
                    af[mi], bfr[ni], acc[mi][ni], 0, 0, 0);
        __syncthreads();
    }

    const int rb = (lane >> 4) * 4;
    const int cl = lane & 15;
    #pragma unroll
    for (int mi = 0; mi < 4; ++mi) {
        #pragma unroll
        for (int r = 0; r < 4; ++r) {
            const int row = row0 + wrow0 + mi * 16 + rb + r;
            if (row >= M) continue;
            #pragma unroll
            for (int ni = 0; ni < 4; ++ni) {
                const int col = col0 + wcol0 + ni * 16 + cl;
                const float v = acc[mi][ni][r];
                if constexpr (EPI == 0) {
                    ((u16*)O1)[(size_t)row * N + col] = f2b(fmaxf(v + bias[col], 0.f));
                } else {
                    ((u16*)O1)[(size_t)row * N + col] = f2b(v);
                }
            }
        }
    }
}

// ---------------------------------------------------------------------------
extern "C" void kernel_launch(void* const* d_in, const int* in_sizes, int n_in,
                              void* d_out, int out_size, void* d_ws, size_t ws_size,
                              hipStream_t stream)
{
    const float* x  = (const float*)d_in[0];
    const int*   ei = (const int*)d_in[1];   // [2, E]: src row then dst row
    const float* W1 = (const float*)d_in[2];
    const float* b1 = (const float*)d_in[3];
    const float* W2 = (const float*)d_in[4];
    const float* b2 = (const float*)d_in[5];
    float* out = (float*)d_out;

    // workspace layout (bytes, all 128-aligned):
    char* ws = (char*)d_ws;
    float* dinv = (float*)(ws + 0);            //    400,000 -> 400,128
    int*   cnt  = (int*)  (ws + 400128);       //    400,000 -> 800,128 (reused as cursor)
    int*   offs = (int*)  (ws + 800128);       //    400,004 -> 1,200,256
    int*   bsum = (int*)  (ws + 1200256);      //        512 -> 1,200,768
    u32x2* recS = (u32x2*)(ws + 1200768);      //  5,120,000 -> 6,320,768  (packed src+wt)
    u32*   xb   = (u32*)  (ws + 6320768);      // 25,600,000 -> 31,920,768  (x bf16)
    u32*   zb   = (u32*)  (ws + 31920768);     // 25,600,000 -> 57,520,768  (Ax bf16)
    u16*   hb   = (u16*)  (ws + 57520768);     // 51,200,000 -> 108,720,768 (h bf16)
    u16*   W1t  = (u16*)  (ws + 108720768);    //     65,536 -> 108,786,304
    u16*   W2t  = (u16*)  (ws + 108786304);    //     32,768 -> 108,819,072
    u16*   xwb  = (u16*)  (ws + 108819072);    // 12,800,000 -> 121,619,072 (xw2 bf16)

    // ---- fused pre-pass (partitioned deg atomics || x->bf16 || W->bf16^T) ----
    hipMemsetAsync(cnt, 0, NND * sizeof(int), stream);
    fused_pre<<<15196, 256, 0, stream>>>(ei, cnt, x, xb, W1, W2, W1t, W2t);

    // ---- CSR build ----
    scanA_dinv<<<NSCAN_B, 256, 0, stream>>>(cnt, offs, bsum, dinv);
    scanC2<<<(NND + 255) / 256, 256, 0, stream>>>(offs, bsum, cnt);
    fill_part<<<NPART * NCHUNK, 256, 0, stream>>>(ei, dinv, cnt, recS);

    // ---- layer 1: z = A~ x (bf16 gather, 4 nodes/wave), h = relu(z@W1+b1) ----
    gather128b<<<(NND * 16 + 255) / 256, 256, 0, stream>>>(
        offs, recS, dinv, (const u32x4*)xb, (u32x4*)zb);
    gemm_mfma<128, 128, 2, 2, 0><<<dim3(782, 2), 256, 0, stream>>>(
        (const u16*)zb, W1t, b1, hb, NND, 256, 128);

    // ---- layer 2: xw2 = h@W2 (bf16); out = b2 + dinv^2*xw2 + gather (8/wave) ----
    gemm_mfma<256, 64, 4, 1, 1><<<dim3(391, 1), 256, 0, stream>>>(
        hb, W2t, nullptr, xwb, NND, 64, 256);
    gather64b<<<(NND * 8 + 255) / 256, 256, 0, stream>>>(
        offs, recS, dinv, (const u32x4*)xwb, b2, out);
}

// Round 12
// 185.347 us; speedup vs baseline: 1.2341x; 1.0213x over previous
//
#include <hip/hip_runtime.h>
#include <cstdint>
#include <cstddef>

#define NND 100000
#define NED 640000
#define NSCAN_B 98          // ceil(NND/1024)
#define NPART 8             // dst-space partitions (== XCDs)
#define PSZ 12500           // NND / NPART
#define NCHUNK 313          // ceil(NED/2048)
#define CVT_B 3125          // cvt_x blocks: 3,200,000 float4 / 1024 per block
#define FILLB (NPART * NCHUNK)          // 2504
#define CVT0  FILLB                      // first cvt_x block (2504)
#define WCVT0 (FILLB + CVT_B)            // first cvt_w block (5629)
#define FCV_N (WCVT0 + 192)              // 5821 total fill_cvt blocks

typedef unsigned int u32;
typedef unsigned short u16;
typedef __attribute__((ext_vector_type(8))) short bf16x8;
typedef __attribute__((ext_vector_type(4))) float f32x4;
typedef __attribute__((ext_vector_type(2))) u32 u32x2;
typedef __attribute__((ext_vector_type(4))) u32 u32x4;

// ---------------------------------------------------------------------------
// helpers: fp32 <-> bf16 (RNE), async global->LDS 16B
// ---------------------------------------------------------------------------
__device__ __forceinline__ u16 f2b(float f) {
    u32 u = __float_as_uint(f);
    return (u16)((u + 0x7fffu + ((u >> 16) & 1u)) >> 16);
}
__device__ __forceinline__ float b2f(u16 b) {
    return __uint_as_float(((u32)b) << 16);
}
__device__ __forceinline__ u32 pack2(float a, float b) {
    return (u32)f2b(a) | ((u32)f2b(b) << 16);
}
__device__ __forceinline__ void gload16(u16* lds, const u16* g) {
    __builtin_amdgcn_global_load_lds(
        (const __attribute__((address_space(1))) u32*)g,
        (__attribute__((address_space(3))) u32*)lds,
        16, 0, 0);
}

// ---------------------------------------------------------------------------
// degree histogram: 16 edges/thread (4x int4), 157 fat blocks.
// Separate kernel -> isolated dur/WRITE_SIZE measurement.
// ---------------------------------------------------------------------------
__global__ __launch_bounds__(256)
void deg_grid(const int* __restrict__ ei, int* __restrict__ cnt) {
    const int e0 = (blockIdx.x * 256 + threadIdx.x) * 16;
    if (e0 >= NED) return;
    #pragma unroll
    for (int j = 0; j < 4; ++j) {
        const int4 d = *(const int4*)&ei[NED + e0 + j * 4];
        atomicAdd(&cnt[d.x], 1);
        atomicAdd(&cnt[d.y], 1);
        atomicAdd(&cnt[d.z], 1);
        atomicAdd(&cnt[d.w], 1);
    }
}

// ---------------------------------------------------------------------------
// scanA + dinv fused: per-1024 exclusive scan of cnt -> offs, block sums,
// and dinv[i] = rsqrt(1+cnt[i])
// ---------------------------------------------------------------------------
__global__ __launch_bounds__(256)
void scanA_dinv(const int* __restrict__ cnt, int* __restrict__ offs,
                int* __restrict__ bsum, float* __restrict__ dinv) {
    __shared__ int s[256];
    const int t = threadIdx.x;
    const int base = blockIdx.x * 1024 + t * 4;
    int c0 = (base + 0 < NND) ? cnt[base + 0] : 0;
    int c1 = (base + 1 < NND) ? cnt[base + 1] : 0;
    int c2 = (base + 2 < NND) ? cnt[base + 2] : 0;
    int c3 = (base + 3 < NND) ? cnt[base + 3] : 0;
    if (base + 0 < NND) dinv[base + 0] = rsqrtf(1.0f + (float)c0);
    if (base + 1 < NND) dinv[base + 1] = rsqrtf(1.0f + (float)c1);
    if (base + 2 < NND) dinv[base + 2] = rsqrtf(1.0f + (float)c2);
    if (base + 3 < NND) dinv[base + 3] = rsqrtf(1.0f + (float)c3);
    const int local = c0 + c1 + c2 + c3;
    s[t] = local;
    __syncthreads();
    for (int off = 1; off < 256; off <<= 1) {
        int v = (t >= off) ? s[t - off] : 0;
        __syncthreads();
        s[t] += v;
        __syncthreads();
    }
    const int excl = s[t] - local;
    if (t == 255) bsum[blockIdx.x] = s[255];
    if (base + 0 < NND) offs[base + 0] = excl;
    if (base + 1 < NND) offs[base + 1] = excl + c0;
    if (base + 2 < NND) offs[base + 2] = excl + c0 + c1;
    if (base + 3 < NND) offs[base + 3] = excl + c0 + c1 + c2;
}

// scanC2: each block redundantly prefixes the 98 block sums, then applies;
// cursor (=cnt reused) initialized to final offset.
__global__ __launch_bounds__(256)
void scanC2(int* __restrict__ offs, const int* __restrict__ bsum,
            int* __restrict__ cursor) {
    __shared__ int pref[NSCAN_B];
    if (threadIdx.x < NSCAN_B) pref[threadIdx.x] = bsum[threadIdx.x];
    __syncthreads();
    if (threadIdx.x == 0) {
        int run = 0;
        #pragma unroll 1
        for (int b = 0; b < NSCAN_B; ++b) { int v = pref[b]; pref[b] = run; run += v; }
    }
    __syncthreads();
    const int i = blockIdx.x * 256 + threadIdx.x;
    if (i < NND) {
        const int v = offs[i] + pref[i >> 10];
        offs[i] = v;
        cursor[i] = v;
    }
    if (i == 0) offs[NND] = NED;
}

// ---------------------------------------------------------------------------
// fill + cvt fused:
//   blocks [0, 2504):      dst-partitioned CSR fill (proven in r10)
//   blocks [2504, 5629):   cvt x->bf16, 4 float4/thread (3,200,000 float4 exact)
//   blocks [5629, 5821):   cvt W1,W2 -> transposed bf16
// cvt overlaps fill instead of serializing before the scan.
// ---------------------------------------------------------------------------
__global__ __launch_bounds__(256)
void fill_cvt(const int* __restrict__ ei, const float* __restrict__ dinv,
              int* __restrict__ cursor, u32x2* __restrict__ recS,
              const float* __restrict__ x, u32* __restrict__ xb,
              const float* __restrict__ W1, const float* __restrict__ W2,
              u16* __restrict__ W1t, u16* __restrict__ W2t) {
    const int b = blockIdx.x;
    if (b < FILLB) {
        const int part = b & 7, chunk = b >> 3;
        const int lo = part * PSZ, hi = lo + PSZ;
        const int e0 = chunk * 2048 + threadIdx.x * 8;
        if (e0 >= NED) return;
        const int4 s0 = *(const int4*)&ei[e0];
        const int4 s1 = *(const int4*)&ei[e0 + 4];
        const int4 d0 = *(const int4*)&ei[NED + e0];
        const int4 d1 = *(const int4*)&ei[NED + e0 + 4];
        const int sv[8] = {s0.x, s0.y, s0.z, s0.w, s1.x, s1.y, s1.z, s1.w};
        const int dv[8] = {d0.x, d0.y, d0.z, d0.w, d1.x, d1.y, d1.z, d1.w};
        #pragma unroll
        for (int j = 0; j < 8; ++j) {
            if (dv[j] >= lo && dv[j] < hi) {
                const int p = atomicAdd(&cursor[dv[j]], 1);
                u32x2 rec = {(u32)sv[j], __float_as_uint(dinv[sv[j]] * dinv[dv[j]])};
                recS[p] = rec;
            }
        }
    } else if (b < WCVT0) {
        const int cb = b - CVT0;                    // 0..3124
        const float4* __restrict__ x4 = (const float4*)x;
        #pragma unroll
        for (int j = 0; j < 4; ++j) {
            const int f4 = cb * 1024 + j * 256 + threadIdx.x;   // float4 index
            if (f4 < 3200000) {
                const float4 v = x4[f4];
                xb[(size_t)f4 * 2 + 0] = pack2(v.x, v.y);
                xb[(size_t)f4 * 2 + 1] = pack2(v.z, v.w);
            }
        }
    } else {
        const int i = (b - WCVT0) * 256 + threadIdx.x;          // < 49,152 exact
        if (i < 128 * 256) {
            const int k = i >> 8, n = i & 255;
            W1t[n * 128 + k] = f2b(W1[i]);
        } else {
            const int j = i - 128 * 256;                        // j < 256*64
            const int k = j >> 6, n = j & 63;
            W2t[n * 256 + k] = f2b(W2[j]);
        }
    }
}

// ---------------------------------------------------------------------------
// CSR gather (bf16), 8-wide predicated edge groups, packed edge records.
// FOUR nodes per wave: 16 lanes x u32x4 (16B) = 256B row.
// z[d] = dinv[d]^2*x[d] + sum_e wt[e]*x[src[e]]
// ---------------------------------------------------------------------------
__global__ __launch_bounds__(256)
void gather128b(const int* __restrict__ offs, const u32x2* __restrict__ recS,
                const float* __restrict__ dinv,
                const u32x4* __restrict__ xb4, u32x4* __restrict__ zb4) {
    const int t    = blockIdx.x * 256 + threadIdx.x;
    const int d    = t >> 4;
    const int lane = t & 15;
    if (d >= NND) return;
    const int beg = offs[d], end = offs[d + 1];
    const float dd = dinv[d];
    const u32x4 s = xb4[(size_t)d * 16 + lane];
    const float d2 = dd * dd;
    float a0 = b2f((u16)s.x) * d2, a1 = b2f((u16)(s.x >> 16)) * d2;
    float a2 = b2f((u16)s.y) * d2, a3 = b2f((u16)(s.y >> 16)) * d2;
    float a4 = b2f((u16)s.z) * d2, a5 = b2f((u16)(s.z >> 16)) * d2;
    float a6 = b2f((u16)s.w) * d2, a7 = b2f((u16)(s.w >> 16)) * d2;
    for (int e = beg; e < end; e += 8) {
        u32x2 r[8]; float wi[8]; u32x4 vi[8];
        #pragma unroll
        for (int j = 0; j < 8; ++j) {
            const int ee = e + j;
            r[j] = __builtin_nontemporal_load(&recS[(ee < end) ? ee : (end - 1)]);
        }
        #pragma unroll
        for (int j = 0; j < 8; ++j) {
            wi[j] = (e + j < end) ? __uint_as_float(r[j].y) : 0.0f;
            vi[j] = xb4[(size_t)r[j].x * 16 + lane];
        }
        #pragma unroll
        for (int j = 0; j < 8; ++j) {
            a0 = fmaf(wi[j], b2f((u16)vi[j].x), a0);
            a1 = fmaf(wi[j], b2f((u16)(vi[j].x >> 16)), a1);
            a2 = fmaf(wi[j], b2f((u16)vi[j].y), a2);
            a3 = fmaf(wi[j], b2f((u16)(vi[j].y >> 16)), a3);
            a4 = fmaf(wi[j], b2f((u16)vi[j].z), a4);
            a5 = fmaf(wi[j], b2f((u16)(vi[j].z >> 16)), a5);
            a6 = fmaf(wi[j], b2f((u16)vi[j].w), a6);
            a7 = fmaf(wi[j], b2f((u16)(vi[j].w >> 16)), a7);
        }
    }
    u32x4 o = {pack2(a0, a1), pack2(a2, a3), pack2(a4, a5), pack2(a6, a7)};
    zb4[(size_t)d * 16 + lane] = o;
}

// out[d] = b2 + dinv[d]^2*xw2[d] + sum_e wt[e]*xw2[src[e]]
// EIGHT nodes per wave: 8 lanes x u32x4 (16B) = 128B row. WRITE-ONLY out.
__global__ __launch_bounds__(256)
void gather64b(const int* __restrict__ offs, const u32x2* __restrict__ recS,
               const float* __restrict__ dinv, const u32x4* __restrict__ xw4,
               const float* __restrict__ b2, float* __restrict__ out) {
    const int t    = blockIdx.x * 256 + threadIdx.x;
    const int d    = t >> 3;
    const int lane = t & 7;
    if (d >= NND) return;
    const int beg = offs[d], end = offs[d + 1];
    const float dd = dinv[d];
    const float d2 = dd * dd;
    const u32x4 s = xw4[(size_t)d * 8 + lane];
    const float4 bl = *(const float4*)&b2[lane * 8];
    const float4 bh = *(const float4*)&b2[lane * 8 + 4];
    float a0 = fmaf(d2, b2f((u16)s.x), bl.x), a1 = fmaf(d2, b2f((u16)(s.x >> 16)), bl.y);
    float a2 = fmaf(d2, b2f((u16)s.y), bl.z), a3 = fmaf(d2, b2f((u16)(s.y >> 16)), bl.w);
    float a4 = fmaf(d2, b2f((u16)s.z), bh.x), a5 = fmaf(d2, b2f((u16)(s.z >> 16)), bh.y);
    float a6 = fmaf(d2, b2f((u16)s.w), bh.z), a7 = fmaf(d2, b2f((u16)(s.w >> 16)), bh.w);
    for (int e = beg; e < end; e += 8) {
        u32x2 r[8]; float wi[8]; u32x4 vi[8];
        #pragma unroll
        for (int j = 0; j < 8; ++j) {
            const int ee = e + j;
            r[j] = __builtin_nontemporal_load(&recS[(ee < end) ? ee : (end - 1)]);
        }
        #pragma unroll
        for (int j = 0; j < 8; ++j) {
            wi[j] = (e + j < end) ? __uint_as_float(r[j].y) : 0.0f;
            vi[j] = xw4[(size_t)r[j].x * 8 + lane];
        }
        #pragma unroll
        for (int j = 0; j < 8; ++j) {
            a0 = fmaf(wi[j], b2f((u16)vi[j].x), a0);
            a1 = fmaf(wi[j], b2f((u16)(vi[j].x >> 16)), a1);
            a2 = fmaf(wi[j], b2f((u16)vi[j].y), a2);
            a3 = fmaf(wi[j], b2f((u16)(vi[j].y >> 16)), a3);
            a4 = fmaf(wi[j], b2f((u16)vi[j].z), a4);
            a5 = fmaf(wi[j], b2f((u16)(vi[j].z >> 16)), a5);
            a6 = fmaf(wi[j], b2f((u16)vi[j].w), a6);
            a7 = fmaf(wi[j], b2f((u16)(vi[j].w >> 16)), a7);
        }
    }
    float* p = &out[(size_t)d * 64 + lane * 8];
    *(float4*)(p + 0) = make_float4(a0, a1, a2, a3);
    *(float4*)(p + 4) = make_float4(a4, a5, a6, a7);
}

// ---------------------------------------------------------------------------
// bf16 MFMA GEMM: C = A[M][K] @ Bt[N][K]^T, 4 waves, 64x64 per wave, BK=32.
// EPI 0: O1(bf16) = relu(acc + bias[col])   (layer-1 h)
// EPI 1: O1(bf16) = acc                      (layer-2 xw2; self+bias in gather)
// ---------------------------------------------------------------------------
template<int BM, int BN, int WM, int WN, int EPI>
__global__ __launch_bounds__(256)
void gemm_mfma(const u16* __restrict__ A, const u16* __restrict__ Bt,
               const float* __restrict__ bias,
               void* __restrict__ O1,
               int M, int N, int K)
{
    __shared__ __align__(16) u16 As[BM * 32];
    __shared__ __align__(16) u16 Bs[BN * 32];
    const int tid  = threadIdx.x;
    const int lane = tid & 63;
    const int wid  = tid >> 6;
    const int wm   = wid % WM;
    const int wn   = wid / WM;
    const int row0 = blockIdx.x * BM;
    const int col0 = blockIdx.y * BN;
    const int wrow0 = wm * 64, wcol0 = wn * 64;

    f32x4 acc[4][4];
    #pragma unroll
    for (int i = 0; i < 4; ++i)
        #pragma unroll
        for (int j = 0; j < 4; ++j) acc[i][j] = (f32x4){0.f, 0.f, 0.f, 0.f};

    const int lr = lane >> 2;          // 0..15: row within 16-row load chunk
    const int lk = (lane & 3) * 8;     // k-element offset (16B granule)

    for (int kt = 0; kt < K; kt += 32) {
        #pragma unroll
        for (int j = 0; j < BM / 64; ++j) {
            const int li = wid * (BM / 64) + j;            // 16 rows per load
            const int r  = li * 16 + lr;
            const int rg = (row0 + r < M) ? (row0 + r) : (M - 1);
            gload16(&As[li * 512], &A[(size_t)rg * K + kt + lk]);
        }
        #pragma unroll
        for (int j = 0; j < BN / 64; ++j) {
            const int li = wid * (BN / 64) + j;
            const int n  = li * 16 + lr;
            gload16(&Bs[li * 512], &Bt[(size_t)(col0 + n) * K + kt + lk]);
        }
        __syncthreads();

        bf16x8 af[4], bfr[4];
        #pragma unroll
        for (int mi = 0; mi < 4; ++mi)
            af[mi] = *(const bf16x8*)&As[(wrow0 + mi * 16 + (lane & 15)) * 32 + (lane >> 4) * 8];
        #pragma unroll
        for (int ni = 0; ni < 4; ++ni)
            bfr[ni] = *(const bf16x8*)&Bs[(wcol0 + ni * 16 + (lane & 15)) * 32 + (lane >> 4) * 8];
        #pragma unroll
        for (int mi = 0; mi < 4; ++mi)
            #pragma unroll
            for (int ni = 0; ni < 4; ++ni)
                acc[mi][ni] = __builtin_amdgcn_mfma_f32_16x16x32_bf16(
                    af[mi], bfr[ni], acc[mi][ni], 0, 0, 0);
        __syncthreads();
    }

    const int rb = (lane >> 4) * 4;
    const int cl = lane & 15;
    #pragma unroll
    for (int mi = 0; mi < 4; ++mi) {
        #pragma unroll
        for (int r = 0; r < 4; ++r) {
            const int row = row0 + wrow0 + mi * 16 + rb + r;
            if (row >= M) continue;
            #pragma unroll
            for (int ni = 0; ni < 4; ++ni) {
                const int col = col0 + wcol0 + ni * 16 + cl;
                const float v = acc[mi][ni][r];
                if constexpr (EPI == 0) {
                    ((u16*)O1)[(size_t)row * N + col] = f2b(fmaxf(v + bias[col], 0.f));
                } else {
                    ((u16*)O1)[(size_t)row * N + col] = f2b(v);
                }
            }
        }
    }
}

// ---------------------------------------------------------------------------
extern "C" void kernel_launch(void* const* d_in, const int* in_sizes, int n_in,
                              void* d_out, int out_size, void* d_ws, size_t ws_size,
                              hipStream_t stream)
{
    const float* x  = (const float*)d_in[0];
    const int*   ei = (const int*)d_in[1];   // [2, E]: src row then dst row
    const float* W1 = (const float*)d_in[2];
    const float* b1 = (const float*)d_in[3];
    const float* W2 = (const float*)d_in[4];
    const float* b2 = (const float*)d_in[5];
    float* out = (float*)d_out;

    // workspace layout (bytes, all 128-aligned):
    char* ws = (char*)d_ws;
    float* dinv = (float*)(ws + 0);            //    400,000 -> 400,128
    int*   cnt  = (int*)  (ws + 400128);       //    400,000 -> 800,128 (reused as cursor)
    int*   offs = (int*)  (ws + 800128);       //    400,004 -> 1,200,256
    int*   bsum = (int*)  (ws + 1200256);      //        512 -> 1,200,768
    u32x2* recS = (u32x2*)(ws + 1200768);      //  5,120,000 -> 6,320,768  (packed src+wt)
    u32*   xb   = (u32*)  (ws + 6320768);      // 25,600,000 -> 31,920,768  (x bf16)
    u32*   zb   = (u32*)  (ws + 31920768);     // 25,600,000 -> 57,520,768  (Ax bf16)
    u16*   hb   = (u16*)  (ws + 57520768);     // 51,200,000 -> 108,720,768 (h bf16)
    u16*   W1t  = (u16*)  (ws + 108720768);    //     65,536 -> 108,786,304
    u16*   W2t  = (u16*)  (ws + 108786304);    //     32,768 -> 108,819,072
    u16*   xwb  = (u16*)  (ws + 108819072);    // 12,800,000 -> 121,619,072 (xw2 bf16)

    // ---- degree histogram (isolated measurement) ----
    hipMemsetAsync(cnt, 0, NND * sizeof(int), stream);
    deg_grid<<<157, 256, 0, stream>>>(ei, cnt);

    // ---- CSR scan ----
    scanA_dinv<<<NSCAN_B, 256, 0, stream>>>(cnt, offs, bsum, dinv);
    scanC2<<<(NND + 255) / 256, 256, 0, stream>>>(offs, bsum, cnt);

    // ---- fill (dst-partitioned) || cvt x->bf16 || cvt W->bf16^T ----
    fill_cvt<<<FCV_N, 256, 0, stream>>>(ei, dinv, cnt, recS,
                                        x, xb, W1, W2, W1t, W2t);

    // ---- layer 1: z = A~ x (bf16 gather, 4 nodes/wave), h = relu(z@W1+b1) ----
    gather128b<<<(NND * 16 + 255) / 256, 256, 0, stream>>>(
        offs, recS, dinv, (const u32x4*)xb, (u32x4*)zb);
    gemm_mfma<128, 128, 2, 2, 0><<<dim3(782, 2), 256, 0, stream>>>(
        (const u16*)zb, W1t, b1, hb, NND, 256, 128);

    // ---- layer 2: xw2 = h@W2 (bf16); out = b2 + dinv^2*xw2 + gather (8/wave) ----
    gemm_mfma<256, 64, 4, 1, 1><<<dim3(391, 1), 256, 0, stream>>>(
        hb, W2t, nullptr, xwb, NND, 64, 256);
    gather64b<<<(NND * 8 + 255) / 256, 256, 0, stream>>>(
        offs, recS, dinv, (const u32x4*)xwb, b2, out);
}

// Round 13
// 173.699 us; speedup vs baseline: 1.3169x; 1.0671x over previous
//
#include <hip/hip_runtime.h>
#include <cstdint>
#include <cstddef>

#define NND 100000
#define NED 640000
#define NSCAN_B 98          // ceil(NND/1024)
#define NPART 8             // dst-space partitions (== XCDs)
#define PSZ 12500           // NND / NPART
#define NCHUNK 313          // ceil(NED/2048)
#define DEGB 625            // deg blocks: 625*256*4 = 640,000 edges exact
#define CVT_B 3125          // cvt_x blocks: 3,200,000 float4 / 1024 per block
#define CVT0  DEGB                       // first cvt_x block (625)
#define WCVT0 (DEGB + CVT_B)             // first cvt_w block (3750)
#define PRE_N (WCVT0 + 192)              // 3942 total pre_all blocks
#define FILLB (NPART * NCHUNK)           // 2504 fill blocks

typedef unsigned int u32;
typedef unsigned short u16;
typedef __attribute__((ext_vector_type(8))) short bf16x8;
typedef __attribute__((ext_vector_type(4))) float f32x4;
typedef __attribute__((ext_vector_type(2))) u32 u32x2;
typedef __attribute__((ext_vector_type(4))) u32 u32x4;

// ---------------------------------------------------------------------------
// helpers: fp32 <-> bf16 (RNE), async global->LDS 16B
// ---------------------------------------------------------------------------
__device__ __forceinline__ u16 f2b(float f) {
    u32 u = __float_as_uint(f);
    return (u16)((u + 0x7fffu + ((u >> 16) & 1u)) >> 16);
}
__device__ __forceinline__ float b2f(u16 b) {
    return __uint_as_float(((u32)b) << 16);
}
__device__ __forceinline__ u32 pack2(float a, float b) {
    return (u32)f2b(a) | ((u32)f2b(b) << 16);
}
__device__ __forceinline__ void gload16(u16* lds, const u16* g) {
    __builtin_amdgcn_global_load_lds(
        (const __attribute__((address_space(1))) u32*)g,
        (__attribute__((address_space(3))) u32*)lds,
        16, 0, 0);
}

// ---------------------------------------------------------------------------
// pre_all fused kernel — the ONE atomic pass, overlapped with the converts:
//   blocks [0, 625):       deg histogram; rank[e] = atomicAdd(&cnt[dst],1)
//                          (rank makes fill atomic-free — pay the LLC atomic
//                          toll once instead of twice)
//   blocks [625, 3750):    cvt x->bf16 (4 float4/thread, 3,200,000 exact)
//   blocks [3750, 3942):   cvt W1,W2 -> transposed bf16
// ---------------------------------------------------------------------------
__global__ __launch_bounds__(256)
void pre_all(const int* __restrict__ ei, int* __restrict__ cnt,
             int* __restrict__ rank,
             const float* __restrict__ x, u32* __restrict__ xb,
             const float* __restrict__ W1, const float* __restrict__ W2,
             u16* __restrict__ W1t, u16* __restrict__ W2t) {
    const int b = blockIdx.x;
    if (b < DEGB) {
        const int e0 = (b * 256 + threadIdx.x) * 4;       // exact cover of NED
        const int4 d = *(const int4*)&ei[NED + e0];
        int r0 = atomicAdd(&cnt[d.x], 1);
        int r1 = atomicAdd(&cnt[d.y], 1);
        int r2 = atomicAdd(&cnt[d.z], 1);
        int r3 = atomicAdd(&cnt[d.w], 1);
        *(int4*)&rank[e0] = make_int4(r0, r1, r2, r3);
    } else if (b < WCVT0) {
        const int cb = b - CVT0;                          // 0..3124
        const float4* __restrict__ x4 = (const float4*)x;
        #pragma unroll
        for (int j = 0; j < 4; ++j) {
            const int f4 = cb * 1024 + j * 256 + threadIdx.x;   // float4 index
            if (f4 < 3200000) {
                const float4 v = x4[f4];
                xb[(size_t)f4 * 2 + 0] = pack2(v.x, v.y);
                xb[(size_t)f4 * 2 + 1] = pack2(v.z, v.w);
            }
        }
    } else {
        const int i = (b - WCVT0) * 256 + threadIdx.x;    // < 49,152 exact
        if (i < 128 * 256) {
            const int k = i >> 8, n = i & 255;
            W1t[n * 128 + k] = f2b(W1[i]);
        } else {
            const int j = i - 128 * 256;                  // j < 256*64
            const int k = j >> 6, n = j & 63;
            W2t[n * 256 + k] = f2b(W2[j]);
        }
    }
}

// ---------------------------------------------------------------------------
// scanA + dinv fused: per-1024 exclusive scan of cnt -> offs, block sums,
// and dinv[i] = rsqrt(1+cnt[i])
// ---------------------------------------------------------------------------
__global__ __launch_bounds__(256)
void scanA_dinv(const int* __restrict__ cnt, int* __restrict__ offs,
                int* __restrict__ bsum, float* __restrict__ dinv) {
    __shared__ int s[256];
    const int t = threadIdx.x;
    const int base = blockIdx.x * 1024 + t * 4;
    int c0 = (base + 0 < NND) ? cnt[base + 0] : 0;
    int c1 = (base + 1 < NND) ? cnt[base + 1] : 0;
    int c2 = (base + 2 < NND) ? cnt[base + 2] : 0;
    int c3 = (base + 3 < NND) ? cnt[base + 3] : 0;
    if (base + 0 < NND) dinv[base + 0] = rsqrtf(1.0f + (float)c0);
    if (base + 1 < NND) dinv[base + 1] = rsqrtf(1.0f + (float)c1);
    if (base + 2 < NND) dinv[base + 2] = rsqrtf(1.0f + (float)c2);
    if (base + 3 < NND) dinv[base + 3] = rsqrtf(1.0f + (float)c3);
    const int local = c0 + c1 + c2 + c3;
    s[t] = local;
    __syncthreads();
    for (int off = 1; off < 256; off <<= 1) {
        int v = (t >= off) ? s[t - off] : 0;
        __syncthreads();
        s[t] += v;
        __syncthreads();
    }
    const int excl = s[t] - local;
    if (t == 255) bsum[blockIdx.x] = s[255];
    if (base + 0 < NND) offs[base + 0] = excl;
    if (base + 1 < NND) offs[base + 1] = excl + c0;
    if (base + 2 < NND) offs[base + 2] = excl + c0 + c1;
    if (base + 3 < NND) offs[base + 3] = excl + c0 + c1 + c2;
}

// scanC2: each block redundantly prefixes the 98 block sums, then applies.
// (cursor no longer needed — fill is atomic-free via rank.)
__global__ __launch_bounds__(256)
void scanC2(int* __restrict__ offs, const int* __restrict__ bsum) {
    __shared__ int pref[NSCAN_B];
    if (threadIdx.x < NSCAN_B) pref[threadIdx.x] = bsum[threadIdx.x];
    __syncthreads();
    if (threadIdx.x == 0) {
        int run = 0;
        #pragma unroll 1
        for (int b = 0; b < NSCAN_B; ++b) { int v = pref[b]; pref[b] = run; run += v; }
    }
    __syncthreads();
    const int i = blockIdx.x * 256 + threadIdx.x;
    if (i < NND) offs[i] += pref[i >> 10];
    if (i == 0) offs[NND] = NED;
}

// ---------------------------------------------------------------------------
// dst-PARTITIONED, ATOMIC-FREE CSR fill: p = offs[dst] + rank[e].
// Block b = (partition b&7, edge chunk b>>3); only partition p's blocks
// (on XCD p) write the contiguous recS region for that dst range ->
// L2-local accumulation, each line written back once.
// ---------------------------------------------------------------------------
__global__ __launch_bounds__(256)
void fill_part(const int* __restrict__ ei, const int* __restrict__ rank,
               const int* __restrict__ offs, const float* __restrict__ dinv,
               u32x2* __restrict__ recS) {
    const int b = blockIdx.x;
    const int part = b & 7, chunk = b >> 3;
    const int lo = part * PSZ, hi = lo + PSZ;
    const int e0 = chunk * 2048 + threadIdx.x * 8;
    if (e0 >= NED) return;
    const int4 s0 = *(const int4*)&ei[e0];
    const int4 s1 = *(const int4*)&ei[e0 + 4];
    const int4 d0 = *(const int4*)&ei[NED + e0];
    const int4 d1 = *(const int4*)&ei[NED + e0 + 4];
    const int4 r0 = *(const int4*)&rank[e0];
    const int4 r1 = *(const int4*)&rank[e0 + 4];
    const int sv[8] = {s0.x, s0.y, s0.z, s0.w, s1.x, s1.y, s1.z, s1.w};
    const int dv[8] = {d0.x, d0.y, d0.z, d0.w, d1.x, d1.y, d1.z, d1.w};
    const int rv[8] = {r0.x, r0.y, r0.z, r0.w, r1.x, r1.y, r1.z, r1.w};
    #pragma unroll
    for (int j = 0; j < 8; ++j) {
        if (dv[j] >= lo && dv[j] < hi) {
            const int p = offs[dv[j]] + rv[j];
            u32x2 rec = {(u32)sv[j], __float_as_uint(dinv[sv[j]] * dinv[dv[j]])};
            recS[p] = rec;
        }
    }
}

// ---------------------------------------------------------------------------
// CSR gather (bf16), 8-wide predicated edge groups, packed edge records.
// FOUR nodes per wave: 16 lanes x u32x4 (16B) = 256B row.
// z[d] = dinv[d]^2*x[d] + sum_e wt[e]*x[src[e]]
// ---------------------------------------------------------------------------
__global__ __launch_bounds__(256)
void gather128b(const int* __restrict__ offs, const u32x2* __restrict__ recS,
                const float* __restrict__ dinv,
                const u32x4* __restrict__ xb4, u32x4* __restrict__ zb4) {
    const int t    = blockIdx.x * 256 + threadIdx.x;
    const int d    = t >> 4;
    const int lane = t & 15;
    if (d >= NND) return;
    const int beg = offs[d], end = offs[d + 1];
    const float dd = dinv[d];
    const u32x4 s = xb4[(size_t)d * 16 + lane];
    const float d2 = dd * dd;
    float a0 = b2f((u16)s.x) * d2, a1 = b2f((u16)(s.x >> 16)) * d2;
    float a2 = b2f((u16)s.y) * d2, a3 = b2f((u16)(s.y >> 16)) * d2;
    float a4 = b2f((u16)s.z) * d2, a5 = b2f((u16)(s.z >> 16)) * d2;
    float a6 = b2f((u16)s.w) * d2, a7 = b2f((u16)(s.w >> 16)) * d2;
    for (int e = beg; e < end; e += 8) {
        u32x2 r[8]; float wi[8]; u32x4 vi[8];
        #pragma unroll
        for (int j = 0; j < 8; ++j) {
            const int ee = e + j;
            r[j] = __builtin_nontemporal_load(&recS[(ee < end) ? ee : (end - 1)]);
        }
        #pragma unroll
        for (int j = 0; j < 8; ++j) {
            wi[j] = (e + j < end) ? __uint_as_float(r[j].y) : 0.0f;
            vi[j] = xb4[(size_t)r[j].x * 16 + lane];
        }
        #pragma unroll
        for (int j = 0; j < 8; ++j) {
            a0 = fmaf(wi[j], b2f((u16)vi[j].x), a0);
            a1 = fmaf(wi[j], b2f((u16)(vi[j].x >> 16)), a1);
            a2 = fmaf(wi[j], b2f((u16)vi[j].y), a2);
            a3 = fmaf(wi[j], b2f((u16)(vi[j].y >> 16)), a3);
            a4 = fmaf(wi[j], b2f((u16)vi[j].z), a4);
            a5 = fmaf(wi[j], b2f((u16)(vi[j].z >> 16)), a5);
            a6 = fmaf(wi[j], b2f((u16)vi[j].w), a6);
            a7 = fmaf(wi[j], b2f((u16)(vi[j].w >> 16)), a7);
        }
    }
    u32x4 o = {pack2(a0, a1), pack2(a2, a3), pack2(a4, a5), pack2(a6, a7)};
    zb4[(size_t)d * 16 + lane] = o;
}

// out[d] = b2 + dinv[d]^2*xw2[d] + sum_e wt[e]*xw2[src[e]]
// EIGHT nodes per wave: 8 lanes x u32x4 (16B) = 128B row. WRITE-ONLY out.
__global__ __launch_bounds__(256)
void gather64b(const int* __restrict__ offs, const u32x2* __restrict__ recS,
               const float* __restrict__ dinv, const u32x4* __restrict__ xw4,
               const float* __restrict__ b2, float* __restrict__ out) {
    const int t    = blockIdx.x * 256 + threadIdx.x;
    const int d    = t >> 3;
    const int lane = t & 7;
    if (d >= NND) return;
    const int beg = offs[d], end = offs[d + 1];
    const float dd = dinv[d];
    const float d2 = dd * dd;
    const u32x4 s = xw4[(size_t)d * 8 + lane];
    const float4 bl = *(const float4*)&b2[lane * 8];
    const float4 bh = *(const float4*)&b2[lane * 8 + 4];
    float a0 = fmaf(d2, b2f((u16)s.x), bl.x), a1 = fmaf(d2, b2f((u16)(s.x >> 16)), bl.y);
    float a2 = fmaf(d2, b2f((u16)s.y), bl.z), a3 = fmaf(d2, b2f((u16)(s.y >> 16)), bl.w);
    float a4 = fmaf(d2, b2f((u16)s.z), bh.x), a5 = fmaf(d2, b2f((u16)(s.z >> 16)), bh.y);
    float a6 = fmaf(d2, b2f((u16)s.w), bh.z), a7 = fmaf(d2, b2f((u16)(s.w >> 16)), bh.w);
    for (int e = beg; e < end; e += 8) {
        u32x2 r[8]; float wi[8]; u32x4 vi[8];
        #pragma unroll
        for (int j = 0; j < 8; ++j) {
            const int ee = e + j;
            r[j] = __builtin_nontemporal_load(&recS[(ee < end) ? ee : (end - 1)]);
        }
        #pragma unroll
        for (int j = 0; j < 8; ++j) {
            wi[j] = (e + j < end) ? __uint_as_float(r[j].y) : 0.0f;
            vi[j] = xw4[(size_t)r[j].x * 8 + lane];
        }
        #pragma unroll
        for (int j = 0; j < 8; ++j) {
            a0 = fmaf(wi[j], b2f((u16)vi[j].x), a0);
            a1 = fmaf(wi[j], b2f((u16)(vi[j].x >> 16)), a1);
            a2 = fmaf(wi[j], b2f((u16)vi[j].y), a2);
            a3 = fmaf(wi[j], b2f((u16)(vi[j].y >> 16)), a3);
            a4 = fmaf(wi[j], b2f((u16)vi[j].z), a4);
            a5 = fmaf(wi[j], b2f((u16)(vi[j].z >> 16)), a5);
            a6 = fmaf(wi[j], b2f((u16)vi[j].w), a6);
            a7 = fmaf(wi[j], b2f((u16)(vi[j].w >> 16)), a7);
        }
    }
    float* p = &out[(size_t)d * 64 + lane * 8];
    *(float4*)(p + 0) = make_float4(a0, a1, a2, a3);
    *(float4*)(p + 4) = make_float4(a4, a5, a6, a7);
}

// ---------------------------------------------------------------------------
// bf16 MFMA GEMM: C = A[M][K] @ Bt[N][K]^T, 4 waves, 64x64 per wave, BK=32.
// EPI 0: O1(bf16) = relu(acc + bias[col])   (layer-1 h)
// EPI 1: O1(bf16) = acc                      (layer-2 xw2; self+bias in gather)
// ---------------------------------------------------------------------------
template<int BM, int BN, int WM, int WN, int EPI>
__global__ __launch_bounds__(256)
void gemm_mfma(const u16* __restrict__ A, const u16* __restrict__ Bt,
               const float* __restrict__ bias,
               void* __restrict__ O1,
               int M, int N, int K)
{
    __shared__ __align__(16) u16 As[BM * 32];
    __shared__ __align__(16) u16 Bs[BN * 32];
    const int tid  = threadIdx.x;
    const int lane = tid & 63;
    const int wid  = tid >> 6;
    const int wm   = wid % WM;
    const int wn   = wid / WM;
    const int row0 = blockIdx.x * BM;
    const int col0 = blockIdx.y * BN;
    const int wrow0 = wm * 64, wcol0 = wn * 64;

    f32x4 acc[4][4];
    #pragma unroll
    for (int i = 0; i < 4; ++i)
        #pragma unroll
        for (int j = 0; j < 4; ++j) acc[i][j] = (f32x4){0.f, 0.f, 0.f, 0.f};

    const int lr = lane >> 2;          // 0..15: row within 16-row load chunk
    const int lk = (lane & 3) * 8;     // k-element offset (16B granule)

    for (int kt = 0; kt < K; kt += 32) {
        #pragma unroll
        for (int j = 0; j < BM / 64; ++j) {
            const int li = wid * (BM / 64) + j;            // 16 rows per load
            const int r  = li * 16 + lr;
            const int rg = (row0 + r < M) ? (row0 + r) : (M - 1);
            gload16(&As[li * 512], &A[(size_t)rg * K + kt + lk]);
        }
        #pragma unroll
        for (int j = 0; j < BN / 64; ++j) {
            const int li = wid * (BN / 64) + j;
            const int n  = li * 16 + lr;
            gload16(&Bs[li * 512], &Bt[(size_t)(col0 + n) * K + kt + lk]);
        }
        __syncthreads();

        bf16x8 af[4], bfr[4];
        #pragma unroll
        for (int mi = 0; mi < 4; ++mi)
            af[mi] = *(const bf16x8*)&As[(wrow0 + mi * 16 + (lane & 15)) * 32 + (lane >> 4) * 8];
        #pragma unroll
        for (int ni = 0; ni < 4; ++ni)
            bfr[ni] = *(const bf16x8*)&Bs[(wcol0 + ni * 16 + (lane & 15)) * 32 + (lane >> 4) * 8];
        #pragma unroll
        for (int mi = 0; mi < 4; ++mi)
            #pragma unroll
            for (int ni = 0; ni < 4; ++ni)
                acc[mi][ni] = __builtin_amdgcn_mfma_f32_16x16x32_bf16(
                    af[mi], bfr[ni], acc[mi][ni], 0, 0, 0);
        __syncthreads();
    }

    const int rb = (lane >> 4) * 4;
    const int cl = lane & 15;
    #pragma unroll
    for (int mi = 0; mi < 4; ++mi) {
        #pragma unroll
        for (int r = 0; r < 4; ++r) {
            const int row = row0 + wrow0 + mi * 16 + rb + r;
            if (row >= M) continue;
            #pragma unroll
            for (int ni = 0; ni < 4; ++ni) {
                const int col = col0 + wcol0 + ni * 16 + cl;
                const float v = acc[mi][ni][r];
                if constexpr (EPI == 0) {
                    ((u16*)O1)[(size_t)row * N + col] = f2b(fmaxf(v + bias[col], 0.f));
                } else {
                    ((u16*)O1)[(size_t)row * N + col] = f2b(v);
                }
            }
        }
    }
}

// ---------------------------------------------------------------------------
extern "C" void kernel_launch(void* const* d_in, const int* in_sizes, int n_in,
                              void* d_out, int out_size, void* d_ws, size_t ws_size,
                              hipStream_t stream)
{
    const float* x  = (const float*)d_in[0];
    const int*   ei = (const int*)d_in[1];   // [2, E]: src row then dst row
    const float* W1 = (const float*)d_in[2];
    const float* b1 = (const float*)d_in[3];
    const float* W2 = (const float*)d_in[4];
    const float* b2 = (const float*)d_in[5];
    float* out = (float*)d_out;

    // workspace layout (bytes, all 128-aligned):
    char* ws = (char*)d_ws;
    float* dinv = (float*)(ws + 0);            //    400,000 -> 400,128
    int*   cnt  = (int*)  (ws + 400128);       //    400,000 -> 800,128
    int*   offs = (int*)  (ws + 800128);       //    400,004 -> 1,200,256
    int*   bsum = (int*)  (ws + 1200256);      //        512 -> 1,200,768
    int*   rank = (int*)  (ws + 1200768);      //  2,560,000 -> 3,760,768  (edge rank)
    u32x2* recS = (u32x2*)(ws + 3760768);      //  5,120,000 -> 8,880,768  (packed src+wt)
    u32*   xb   = (u32*)  (ws + 8880768);      // 25,600,000 -> 34,480,768  (x bf16)
    u32*   zb   = (u32*)  (ws + 34480768);     // 25,600,000 -> 60,080,768  (Ax bf16)
    u16*   hb   = (u16*)  (ws + 60080768);     // 51,200,000 -> 111,280,768 (h bf16)
    u16*   W1t  = (u16*)  (ws + 111280768);    //     65,536 -> 111,346,304
    u16*   W2t  = (u16*)  (ws + 111346304);    //     32,768 -> 111,379,072
    u16*   xwb  = (u16*)  (ws + 111379072);    // 12,800,000 -> 124,179,072 (xw2 bf16)

    // ---- the one atomic pass (deg+rank) || cvt x->bf16 || cvt W->bf16^T ----
    hipMemsetAsync(cnt, 0, NND * sizeof(int), stream);
    pre_all<<<PRE_N, 256, 0, stream>>>(ei, cnt, rank, x, xb, W1, W2, W1t, W2t);

    // ---- CSR scan ----
    scanA_dinv<<<NSCAN_B, 256, 0, stream>>>(cnt, offs, bsum, dinv);
    scanC2<<<(NND + 255) / 256, 256, 0, stream>>>(offs, bsum);

    // ---- atomic-free, dst-partitioned fill ----
    fill_part<<<FILLB, 256, 0, stream>>>(ei, rank, offs, dinv, recS);

    // ---- layer 1: z = A~ x (bf16 gather, 4 nodes/wave), h = relu(z@W1+b1) ----
    gather128b<<<(NND * 16 + 255) / 256, 256, 0, stream>>>(
        offs, recS, dinv, (const u32x4*)xb, (u32x4*)zb);
    gemm_mfma<128, 128, 2, 2, 0><<<dim3(782, 2), 256, 0, stream>>>(
        (const u16*)zb, W1t, b1, hb, NND, 256, 128);

    // ---- layer 2: xw2 = h@W2 (bf16); out = b2 + dinv^2*xw2 + gather (8/wave) ----
    gemm_mfma<256, 64, 4, 1, 1><<<dim3(391, 1), 256, 0, stream>>>(
        hb, W2t, nullptr, xwb, NND, 64, 256);
    gather64b<<<(NND * 8 + 255) / 256, 256, 0, stream>>>(
        offs, recS, dinv, (const u32x4*)xwb, b2, out);
}